// Round 11
// baseline (389.399 us; speedup 1.0000x reference)
//
#include <hip/hip_runtime.h>
#include <hip/hip_bf16.h>
#include <math.h>

#define BATCH 2
#define NPTS  8192
#define CIN   32
#define HID   128
#define COUT  64
#define EIN   67
#define KNN   16

#define TILE  1024     // fallback knn candidate tile
#define CAP   128      // survivor cap per point
#define KMARGIN 1e-3f  // scalar-path filter margin (exact f both passes)
#define KM_MFMA 4e-3f  // mfma-path margin: covers 2*eps, eps<=1.4e-3 (split-bf16)

typedef unsigned short u16;
typedef unsigned long long u64;
typedef __attribute__((ext_vector_type(8))) short bf16x8;    // MFMA A/B frag
typedef __attribute__((ext_vector_type(4))) float f32x4;     // MFMA C/D frag (16x16)
typedef __attribute__((ext_vector_type(16))) float f32x16;   // MFMA C/D frag (32x32)

#if defined(__has_builtin)
#if __has_builtin(__builtin_amdgcn_rcpf)
#define USE_RCPF 1
#endif
#endif

__device__ __forceinline__ u16 f2b(float f) {   // RNE fp32->bf16
    unsigned u = __float_as_uint(f);
    return (u16)((u + 0x7FFFu + ((u >> 16) & 1u)) >> 16);
}
__device__ __forceinline__ float b2f(u16 h) {
    return __uint_as_float(((unsigned)h) << 16);
}
__device__ __forceinline__ unsigned pk2(float a, float b) {
    return (unsigned)f2b(a) | ((unsigned)f2b(b) << 16);
}
__device__ __forceinline__ float gelu_t(float x) {
    // tanh-approx GELU via x * e^u/(e^u+1), u = 1.59577(x + 0.044715 x^3)
    float u = 1.5957691216057308f * (x + 0.044715f * x * x * x);
    float ex = __expf(u);
#ifdef USE_RCPF
    return x * ex * __builtin_amdgcn_rcpf(ex + 1.0f);
#else
    return x * ex / (ex + 1.0f);
#endif
}

// 16th-smallest (rank-15 ascending, ties counted) of 64 per-lane values via
// bitonic sort on shuffles (HW-green in knn9/knn11/knn12).
__device__ __forceinline__ float rank16_of_64(float v, int lane) {
#pragma unroll
    for (int k = 2; k <= 64; k <<= 1) {
#pragma unroll
        for (int j = k >> 1; j > 0; j >>= 1) {
            float o = __shfl_xor(v, j, 64);
            bool lower = (lane & j) == 0;
            bool asc   = (lane & k) == 0;   // k=64: ascending everywhere
            float mn = fminf(v, o), mx = fmaxf(v, o);
            v = (lower == asc) ? mn : mx;
        }
    }
    return __shfl(v, 15, 64);
}

// ============== prep: verts -> pv {x,y,z,sq} ==============
__global__ void prep_kernel(const float* __restrict__ verts, float4* __restrict__ pv) {
    int i = blockIdx.x * blockDim.x + threadIdx.x;
    if (i >= BATCH * NPTS) return;
    float x = verts[3 * i], y = verts[3 * i + 1], z = verts[3 * i + 2];
    float sq = __fadd_rn(__fadd_rn(__fmul_rn(x, x), __fmul_rn(y, y)), __fmul_rn(z, z));
    pv[i] = make_float4(x, y, z, sq);
}

// ============== prep2: pv + candidate B-fragments (split-bf16, 32B/cand) ====
// Bytes unchanged from the knn11/knn12 green runs; knn14 reindexes the same
// two uint4s per candidate for the 32x32x16 B layout (k=(lane>>5)*8+j).
__global__ void prep2_kernel(const float* __restrict__ verts,
                             float4* __restrict__ pv, uint4* __restrict__ bfrag) {
    int i = blockIdx.x * blockDim.x + threadIdx.x;
    if (i >= BATCH * NPTS) return;
    float x = verts[3 * i], y = verts[3 * i + 1], z = verts[3 * i + 2];
    float sq = __fadd_rn(__fadd_rn(__fmul_rn(x, x), __fmul_rn(y, y)), __fmul_rn(z, z));
    pv[i] = make_float4(x, y, z, sq);

    u16 xh = f2b(x);  u16 xl = f2b(x - b2f(xh));
    u16 yh = f2b(y);  u16 yl = f2b(y - b2f(yh));
    u16 zh = f2b(z);  u16 zl = f2b(z - b2f(zh));
    u16 ch = f2b(sq); u16 cl = f2b(sq - b2f(ch));

    uint4 lo, hi;
    lo.x = (unsigned)xh | ((unsigned)xl << 16);   // k0,k1
    lo.y = (unsigned)xh | ((unsigned)yh << 16);   // k2,k3
    lo.z = (unsigned)yl | ((unsigned)yh << 16);   // k4,k5
    lo.w = (unsigned)zh | ((unsigned)zl << 16);   // k6,k7
    hi.x = (unsigned)zh | ((unsigned)ch << 16);   // k8,k9
    hi.y = (unsigned)cl;                          // k10,k11=0
    hi.z = 0u; hi.w = 0u;                         // k12..15 = 0 (A zero there too)
    bfrag[(size_t)i * 2]     = lo;
    bfrag[(size_t)i * 2 + 1] = hi;
}

// ============== KNN v14: 32x32x16 MFMA filter + leader-ballot append ========
// Block = 32 points (one 32-row A tile), 512 threads; wave w scans eighth
// [w*1024,(w+1)*1024) at 32 cands per MFMA: 1 uint4 load + 1 mfma_32x32x16
// per 1024 point-cand pairs (4x fewer loads/MFMAs per pair than knn12).
// A: row=lane&31, k=(lane>>5)*8+j (same half-split slots as green knn12).
// D: col=lane&31 (candidate), row(reg r)=(r&3)+8*(r>>2)+4*(lane>>5) [verified
// layout]. tau: per-lane sample mins merged 4:1 in-wave -> 64 bins of 64 over
// stratified 4096 sample (same stats + validity proof as knn12). Survivors
// appended via per-half leader-lane single atomicAdd + prefix. Exact-fp32
// rescore + (d,j)-lex rank (green semantics) picks the final 16.
__global__ __launch_bounds__(512, 2) void knn14_kernel(const float4* __restrict__ pv,
                                                       const uint4* __restrict__ bfrag,
                                                       int* __restrict__ nbr_out_rows) {
    __shared__ float mnsh[8][32][8];     // 8 KB merged bin-mins
    __shared__ float taus[32];
    __shared__ int   cnt[32];
    __shared__ int   sJ[32][CAP];        // 16 KB survivor indices
    __shared__ float bufD[32][CAP];      // 16 KB exact distances (rescore)

    const int tid = threadIdx.x, lane = tid & 63, wv = tid >> 6;   // wv 0..7
    const int cc32 = lane & 31, h = lane >> 5;
    const int ptb = blockIdx.x * 32;
    const int b = ptb >> 13, i0 = ptb & (NPTS - 1);
    const float4* __restrict__ P = pv + (size_t)b * NPTS;
    const uint4* __restrict__ BF = bfrag + (size_t)b * NPTS * 2;

    union U { uint4 u; bf16x8 v; };

    // ---- A-frag: row = lane&31 (point), k = h*8+j ----
    union { bf16x8 v; unsigned w[4]; } A;
    {
        float4 s = P[i0 + cc32];
        float mx = -2.0f * s.x, my = -2.0f * s.y, mz = -2.0f * s.z;
        u16 mxh = f2b(mx); u16 mxl = f2b(mx - b2f(mxh));
        u16 myh = f2b(my); u16 myl = f2b(my - b2f(myh));
        u16 mzh = f2b(mz); u16 mzl = f2b(mz - b2f(mzh));
        if (h == 0) {
            A.w[0] = (unsigned)mxh | ((unsigned)mxh << 16);   // k0,k1
            A.w[1] = (unsigned)mxl | ((unsigned)myh << 16);   // k2,k3
            A.w[2] = (unsigned)myh | ((unsigned)myl << 16);   // k4,k5
            A.w[3] = (unsigned)mzh | ((unsigned)mzh << 16);   // k6,k7
        } else {
            A.w[0] = (unsigned)mzl | (0x3F80u << 16);         // k8, k9=1.0
            A.w[1] = 0x3F80u;                                 // k10=1.0, k11=0
            A.w[2] = 0u; A.w[3] = 0u;                         // k12..15 = 0
        }
    }

    const int cb = wv * 1024;   // this wave's candidate eighth
    const uint4* __restrict__ bp = BF + ((size_t)(cb + cc32) * 2 + h);

    // ---- tau phase: 16 tiles (512 stratified sample cands/wave) ----
    float mn[16];
#pragma unroll
    for (int r = 0; r < 16; ++r) mn[r] = INFINITY;
    for (int t = 0; t < 16; ++t) {
        U bu; bu.u = bp[(size_t)t * 64];
        f32x16 acc = (f32x16)(0.0f);
        acc = __builtin_amdgcn_mfma_f32_32x32x16_bf16(A.v, bu.v, acc, 0, 0, 0);
#pragma unroll
        for (int r = 0; r < 16; ++r) mn[r] = fminf(mn[r], acc[r]);
    }
    // merge 4:1 within wave (lanes l, l^8, l^16, l^24 share a bin of 64 cands)
#pragma unroll
    for (int r = 0; r < 16; ++r) {
        float v = mn[r];
        v = fminf(v, __shfl_xor(v, 8, 64));
        v = fminf(v, __shfl_xor(v, 16, 64));
        if ((lane & 24) == 0) {
            int row = (r & 3) + 8 * (r >> 2) + 4 * h;
            mnsh[wv][row][lane & 7] = v;
        }
    }
    if (tid < 32) cnt[tid] = 0;
    __syncthreads();

    // ---- tau select: wave wv owns points 4wv..4wv+3; 64 bins each ----
    {
#pragma unroll
        for (int q = 0; q < 4; ++q) {
            const int p = wv * 4 + q;
            float v = mnsh[lane >> 3][p][lane & 7];
            float tq = rank16_of_64(v, lane) + KM_MFMA;
            if (lane == 0) taus[p] = tq;
        }
    }
    __syncthreads();

    float mytau[16];
#pragma unroll
    for (int r = 0; r < 16; ++r)
        mytau[r] = taus[(r & 3) + 8 * (r >> 2) + 4 * h];

    // ---- pass 2: full eighth (32 tiles), bit-identical D, leader append ----
    for (int t = 0; t < 32; ++t) {
        U bu; bu.u = bp[(size_t)t * 64];
        f32x16 acc = (f32x16)(0.0f);
        acc = __builtin_amdgcn_mfma_f32_32x32x16_bf16(A.v, bu.v, acc, 0, 0, 0);
        const int cbase = cb + t * 32;
#pragma unroll
        for (int r = 0; r < 16; ++r) {
            bool pred = (acc[r] <= mytau[r]);
            u64 mk = __ballot(pred);
            if (mk != 0ull) {
                unsigned seg = (unsigned)(mk >> (h * 32));
                if (seg) {
                    const int p = (r & 3) + 8 * (r >> 2) + 4 * h;
                    int leader = (h << 5) + (__ffs(seg) - 1);
                    int base = 0;
                    if (lane == leader) base = atomicAdd(&cnt[p], (int)__popc(seg));
                    base = __shfl(base, leader, 64);
                    if (pred) {
                        int pos = base + (int)__popc(seg & ((1u << cc32) - 1u));
                        if (pos < CAP) sJ[p][pos] = cbase + cc32;
                    }
                }
            }
        }
    }
    __syncthreads();

    // ---- exact fp32 rescore + (d,j)-lex rank (green semantics); 4 pts/wave --
#pragma unroll
    for (int q = 0; q < 4; ++q) {
        const int p = wv * 4 + q;
        int ns = cnt[p]; ns = (ns > CAP) ? CAP : ns;   // >= 16 guaranteed
        const float4 sp = P[i0 + p];
        float dl[2]; int jl[2];
#pragma unroll
        for (int slot = 0; slot < 2; ++slot) {
            int sidx = slot * 64 + lane;
            bool act = sidx < ns;
            int js = act ? sJ[p][sidx] : 0;
            float4 cc = P[js];
            float dot = __fmul_rn(sp.x, cc.x);
            dot = __fmaf_rn(sp.y, cc.y, dot);
            dot = __fmaf_rn(sp.z, cc.z, dot);
            float d = __fsub_rn(__fadd_rn(sp.w, cc.w), __fmul_rn(2.0f, dot));
            if (act) bufD[p][sidx] = d;
            dl[slot] = d; jl[slot] = js;
        }
        int r0 = 0, r1 = 0;
        for (int mm = 0; mm < ns; ++mm) {
            float dm = bufD[p][mm]; int jm = sJ[p][mm];
            r0 += (dm < dl[0]) || (dm == dl[0] && jm < jl[0]);
            r1 += (dm < dl[1]) || (dm == dl[1] && jm < jl[1]);
        }
        if (lane < ns && r0 < KNN)
            nbr_out_rows[(size_t)(ptb + p) * 64 + r0] = jl[0];
        if (64 + lane < ns && r1 < KNN)
            nbr_out_rows[(size_t)(ptb + p) * 64 + r1] = jl[1];
    }
}

// ============== KNN v9 (green 77us): mid fallback if ws < 768KB ==============
__global__ __launch_bounds__(256, 8) void knn9_kernel(const float4* __restrict__ pv,
                                                      int* __restrict__ nbr_out_rows) {
    __shared__ float  bufD[4][2][CAP];
    __shared__ int    bufJ[4][2][CAP];

    const int tid = threadIdx.x, lane = tid & 63, wv = tid >> 6;
    const int pt0 = (blockIdx.x * 4 + wv) * 2;
    const int b = pt0 >> 13, i0 = pt0 & (NPTS - 1);
    const float4* P = pv + (size_t)b * NPTS;

    float4 sp[2];
    float ax[2], ay[2], az[2];
#pragma unroll
    for (int p = 0; p < 2; ++p) {
        sp[p] = P[i0 + p];
        ax[p] = -2.0f * sp[p].x; ay[p] = -2.0f * sp[p].y; az[p] = -2.0f * sp[p].z;
    }

    float mn[2] = {INFINITY, INFINITY};
    for (int t = 0; t < 16; ++t) {
        float4 c0 = P[t * 256 + lane];
        float4 c1 = P[t * 256 + 64 + lane];
        float4 c2 = P[t * 256 + 128 + lane];
        float4 c3 = P[t * 256 + 192 + lane];
#pragma unroll
        for (int p = 0; p < 2; ++p) {
            float f0 = __fmaf_rn(ax[p], c0.x, __fmaf_rn(ay[p], c0.y, __fmaf_rn(az[p], c0.z, c0.w)));
            float f1 = __fmaf_rn(ax[p], c1.x, __fmaf_rn(ay[p], c1.y, __fmaf_rn(az[p], c1.z, c1.w)));
            float f2 = __fmaf_rn(ax[p], c2.x, __fmaf_rn(ay[p], c2.y, __fmaf_rn(az[p], c2.z, c2.w)));
            float f3 = __fmaf_rn(ax[p], c3.x, __fmaf_rn(ay[p], c3.y, __fmaf_rn(az[p], c3.z, c3.w)));
            mn[p] = fminf(fminf(fminf(mn[p], f0), fminf(f1, f2)), f3);
        }
    }

    float tau[2];
#pragma unroll
    for (int p = 0; p < 2; ++p)
        tau[p] = rank16_of_64(mn[p], lane) + KMARGIN;

    int base[2] = {0, 0};
    for (int t = 0; t < 32; ++t) {
        float4 c[4];
#pragma unroll
        for (int k = 0; k < 4; ++k) c[k] = P[t * 256 + k * 64 + lane];
        bool pr[4][2];
        bool anyl = false;
#pragma unroll
        for (int k = 0; k < 4; ++k)
#pragma unroll
            for (int p = 0; p < 2; ++p) {
                float f = __fmaf_rn(ax[p], c[k].x,
                          __fmaf_rn(ay[p], c[k].y,
                          __fmaf_rn(az[p], c[k].z, c[k].w)));
                pr[k][p] = (f <= tau[p]);
                anyl |= pr[k][p];
            }
        if (__ballot(anyl) == 0ull) continue;
#pragma unroll
        for (int k = 0; k < 4; ++k) {
            u64 anyk = __ballot(pr[k][0] | pr[k][1]);
            if (anyk == 0ull) continue;
            int j = t * 256 + k * 64 + lane;
#pragma unroll
            for (int p = 0; p < 2; ++p) {
                u64 mk = __ballot(pr[k][p]);
                if (mk != 0ull) {
                    if (pr[k][p]) {
                        int pos = base[p] + (int)__popcll(mk & ((1ull << lane) - 1ull));
                        if (pos < CAP) bufJ[wv][p][pos] = j;
                    }
                    base[p] += (int)__popcll(mk);
                }
            }
        }
    }

#pragma unroll
    for (int p = 0; p < 2; ++p) {
        int ns = base[p]; ns = (ns > CAP) ? CAP : ns;
        float dloc[2]; int jloc[2];
#pragma unroll
        for (int slot = 0; slot < 2; ++slot) {
            int sidx = slot * 64 + lane;
            bool act = sidx < ns;
            int js = act ? bufJ[wv][p][sidx] : 0;
            float4 cc = P[js];
            float dot = __fmul_rn(sp[p].x, cc.x);
            dot = __fmaf_rn(sp[p].y, cc.y, dot);
            dot = __fmaf_rn(sp[p].z, cc.z, dot);
            float d = __fsub_rn(__fadd_rn(sp[p].w, cc.w), __fmul_rn(2.0f, dot));
            if (act) bufD[wv][p][sidx] = d;
            dloc[slot] = d; jloc[slot] = js;
        }
        int r0 = 0, r1 = 0;
        for (int mm = 0; mm < ns; ++mm) {
            float dm = bufD[wv][p][mm]; int jm = bufJ[wv][p][mm];
            r0 += (dm < dloc[0]) || (dm == dloc[0] && jm < jloc[0]);
            r1 += (dm < dloc[1]) || (dm == dloc[1] && jm < jloc[1]);
        }
        if (lane < ns && r0 < KNN)
            nbr_out_rows[(size_t)(pt0 + p) * 64 + r0] = jloc[0];
        if (64 + lane < ns && r1 < KNN)
            nbr_out_rows[(size_t)(pt0 + p) * 64 + r1] = jloc[1];
    }
}

// ============== KNN fallback (used only if ws too small) ==============
__global__ __launch_bounds__(256) void knn_kernel(const float* __restrict__ verts,
                                                  int* nbr_out_rows) {
    __shared__ float4 tilebuf[TILE];
    __shared__ float  bufD[4][CAP];
    __shared__ int    bufJ[4][CAP];

    const int tid = threadIdx.x, lane = tid & 63, wv = tid >> 6;
    const int pt = blockIdx.x * 4 + wv;
    const int b = pt >> 13, i = pt & (NPTS - 1);
    const float* vb = verts + (size_t)b * NPTS * 3;

    const float xi = vb[3 * i], yi = vb[3 * i + 1], zi = vb[3 * i + 2];
    const float sqi = __fadd_rn(__fadd_rn(__fmul_rn(xi, xi), __fmul_rn(yi, yi)),
                                __fmul_rn(zi, zi));

    float m_d = INFINITY;
    for (int t = 0; t < NPTS / TILE; ++t) {
        __syncthreads();
        for (int s = 0; s < TILE / 256; ++s) {
            int p = t * TILE + s * 256 + tid;
            float px = vb[3 * p], py = vb[3 * p + 1], pz = vb[3 * p + 2];
            float sq = __fadd_rn(__fadd_rn(__fmul_rn(px, px), __fmul_rn(py, py)),
                                 __fmul_rn(pz, pz));
            tilebuf[s * 256 + tid] = make_float4(px, py, pz, sq);
        }
        __syncthreads();
        for (int it = 0; it < TILE / 64; ++it) {
            float4 c = tilebuf[it * 64 + lane];
            float dot = __fmul_rn(xi, c.x);
            dot = __fmaf_rn(yi, c.y, dot);
            dot = __fmaf_rn(zi, c.z, dot);
            float d = __fsub_rn(__fadd_rn(sqi, c.w), __fmul_rn(2.0f, dot));
            m_d = fminf(m_d, d);
        }
    }
    __shared__ float minv[4][64];
    minv[wv][lane] = m_d;
    __syncthreads();
    int rnk = 0;
    for (int mm = 0; mm < 64; ++mm) {
        float vm = minv[wv][mm];
        rnk += (vm < m_d) || (vm == m_d && mm < lane);
    }
    u64 bal = __ballot(rnk == 15);
    float tau = __shfl(m_d, __ffsll(bal) - 1, 64);

    int base = 0;
    for (int t = 0; t < NPTS / TILE; ++t) {
        __syncthreads();
        for (int s = 0; s < TILE / 256; ++s) {
            int p = t * TILE + s * 256 + tid;
            float px = vb[3 * p], py = vb[3 * p + 1], pz = vb[3 * p + 2];
            float sq = __fadd_rn(__fadd_rn(__fmul_rn(px, px), __fmul_rn(py, py)),
                                 __fmul_rn(pz, pz));
            tilebuf[s * 256 + tid] = make_float4(px, py, pz, sq);
        }
        __syncthreads();
        for (int it = 0; it < TILE / 64; ++it) {
            int jl = it * 64 + lane;
            float4 c = tilebuf[jl];
            float dot = __fmul_rn(xi, c.x);
            dot = __fmaf_rn(yi, c.y, dot);
            dot = __fmaf_rn(zi, c.z, dot);
            float d = __fsub_rn(__fadd_rn(sqi, c.w), __fmul_rn(2.0f, dot));
            bool pred = (d <= tau);
            u64 mask = __ballot(pred);
            if (pred) {
                int pos = base + (int)__popcll(mask & ((1ull << lane) - 1ull));
                if (pos < CAP) { bufD[wv][pos] = d; bufJ[wv][pos] = t * TILE + jl; }
            }
            base += (int)__popcll(mask);
        }
    }
    int ns = (base > CAP) ? CAP : base;
    __syncthreads();
#pragma unroll
    for (int slot = 0; slot < 2; ++slot) {
        int sidx = slot * 64 + lane;
        if (sidx < ns) {
            float ds = bufD[wv][sidx];
            int   js = bufJ[wv][sidx];
            int rank = 0;
            for (int mm = 0; mm < ns; ++mm) {
                float dm = bufD[wv][mm];
                int   jm = bufJ[wv][mm];
                rank += (dm < ds) || (dm == ds && jm < js);
            }
            if (rank < KNN) nbr_out_rows[(size_t)pt * 64 + rank] = js;
        }
    }
}

// ============ edge8 v3 (green, r10): W2F in LDS + gather prefetch ============
__global__ __launch_bounds__(512, 2) void edge8_kernel(
    const float* __restrict__ verts, const float* __restrict__ feats,
    const float* __restrict__ W1, const float* __restrict__ b1,
    const float* __restrict__ g1, const float* __restrict__ be1,
    const float* __restrict__ W2, const float* __restrict__ b2,
    const float* __restrict__ Wo1, const float* __restrict__ bo1,
    const float* __restrict__ go_, const float* __restrict__ beo,
    const float* __restrict__ Wo2, const float* __restrict__ bo2,
    float* out)   // rows hold knn idx on entry; final output on exit
{
    __shared__ u16 EPw[8][4][64][8];    // 32 KB: per-wave E/P A-frag region
    __shared__ u16 W1F[3][8][64][8];    // 24 KB (phase2: Wo1 frags in kt 0..1)
    __shared__ u16 W2F[4][4][64][8];    // 8 KB W2 B-frags (phase2: Wo2)
    __shared__ float b1s[HID], g1s[HID], be1s[HID];
    __shared__ float b2s[COUT];
    __shared__ float meansh[32][68];    // 8.5 KB; phase2: staging for out rows

    const int tid  = threadIdx.x;
    const int lane = tid & 63, wv = tid >> 6;    // wv 0..7
    const int quad = lane >> 4, n16 = lane & 15;

    // ---- stage W1 as B-fragments ----
    for (int s = tid; s < 3 * 8 * 64; s += 512) {
        int kt = s >> 9, nt = (s >> 6) & 7, ln = s & 63;
        int q = ln >> 4, nn = ln & 15;
        int col = nt * 16 + nn;
        union { bf16x8 v; unsigned u[4]; } pk;
#pragma unroll
        for (int jj = 0; jj < 4; ++jj) {
            int k0 = kt * 32 + q * 8 + jj * 2;
            float a  = (k0     < EIN) ? W1[(size_t)k0 * HID + col]       : 0.0f;
            float bq = (k0 + 1 < EIN) ? W1[(size_t)(k0 + 1) * HID + col] : 0.0f;
            pk.u[jj] = pk2(a, bq);
        }
        *(bf16x8*)&W1F[kt][nt][ln][0] = pk.v;
    }
    // ---- stage W2 as B-fragments (cooperative; shared across waves) ----
    for (int s = tid; s < 4 * 4 * 64; s += 512) {
        int kt2 = s >> 8, nt2 = (s >> 6) & 3, ln = s & 63;
        int q = ln >> 4, nn = ln & 15;
        int o = nt2 * 16 + nn;
        union { bf16x8 v; unsigned u[4]; } pk;
#pragma unroll
        for (int jj = 0; jj < 4; ++jj) {
            int k0 = kt2 * 32 + q * 8 + jj * 2;
            pk.u[jj] = pk2(W2[(size_t)k0 * COUT + o],
                           W2[(size_t)(k0 + 1) * COUT + o]);
        }
        *(bf16x8*)&W2F[kt2][nt2][ln][0] = pk.v;
    }
    if (tid < HID) { b1s[tid] = b1[tid]; g1s[tid] = g1[tid]; be1s[tid] = be1[tid]; }
    if (tid >= HID && tid < HID + COUT) b2s[tid - HID] = b2[tid - HID];
    __syncthreads();   // W1F + W2F + biases visible to all waves

    const int ptb = blockIdx.x * 32;
    const int bb  = ptb >> 13;
    const float* fb  = feats + (size_t)bb * NPTS * CIN;
    const float* vbk = verts + (size_t)bb * NPTS * 3;
    const int ptw = ptb + wv * 4;              // this wave's 4 points
    const int ipw = ptw & (NPTS - 1);

    // hoisted LN operands (point-independent)
    float b1v[8], g1v[8], bev[8];
#pragma unroll
    for (int nt = 0; nt < 8; ++nt) {
        b1v[nt] = b1s[nt * 16 + n16];
        g1v[nt] = g1s[nt * 16 + n16];
        bev[nt] = be1s[nt * 16 + n16];
    }

    const int k16 = lane & 15;
    const int qq  = lane >> 4;

    int jnv[4];
#pragma unroll
    for (int pp = 0; pp < 4; ++pp)
        jnv[pp] = ((const int*)out)[(size_t)(ptw + pp) * 64 + k16];

    // ---- preload pp=0 gathers ----
    float4 nA, nB, sA, sB;
    float rx = 0.f, ry = 0.f, rz = 0.f;
    {
        const int jn = jnv[0], ipn = ipw;
        const float* nsrc = fb + (size_t)jn * CIN + qq * 8;
        nA = *(const float4*)nsrc; nB = *(const float4*)(nsrc + 4);
        const float* ssrc = fb + (size_t)ipn * CIN + qq * 8;
        sA = *(const float4*)ssrc; sB = *(const float4*)(ssrc + 4);
        if (qq == 0) {
            rx = vbk[3 * jn]     - vbk[3 * ipn];
            ry = vbk[3 * jn + 1] - vbk[3 * ipn + 1];
            rz = vbk[3 * jn + 2] - vbk[3 * ipn + 2];
        }
    }

#pragma unroll
    for (int pp = 0; pp < 4; ++pp) {
        // ---- pack + store E from prefetched regs (3 b128 per lane) ----
        {
            union { bf16x8 v; unsigned u[4]; } e0, e1, e2;
            e0.u[0] = pk2(nA.x, nA.y); e0.u[1] = pk2(nA.z, nA.w);
            e0.u[2] = pk2(nB.x, nB.y); e0.u[3] = pk2(nB.z, nB.w);
            e1.u[0] = pk2(sA.x, sA.y); e1.u[1] = pk2(sA.z, sA.w);
            e1.u[2] = pk2(sB.x, sB.y); e1.u[3] = pk2(sB.z, sB.w);
            e2.u[0] = e2.u[1] = e2.u[2] = e2.u[3] = 0u;
            if (qq == 0) { e2.u[0] = pk2(rx, ry); e2.u[1] = pk2(rz, 0.0f); }
            *(bf16x8*)&EPw[wv][0][lane][0] = e0.v;
            *(bf16x8*)&EPw[wv][1][lane][0] = e1.v;
            *(bf16x8*)&EPw[wv][2][lane][0] = e2.v;
        }

        // ---- issue NEXT point's gathers; latency hides under compute below ----
        if (pp < 3) {
            const int jn = jnv[pp + 1], ipn = ipw + pp + 1;
            const float* nsrc = fb + (size_t)jn * CIN + qq * 8;
            nA = *(const float4*)nsrc; nB = *(const float4*)(nsrc + 4);
            const float* ssrc = fb + (size_t)ipn * CIN + qq * 8;
            sA = *(const float4*)ssrc; sB = *(const float4*)(ssrc + 4);
            if (qq == 0) {
                rx = vbk[3 * jn]     - vbk[3 * ipn];
                ry = vbk[3 * jn + 1] - vbk[3 * ipn + 1];
                rz = vbk[3 * jn + 2] - vbk[3 * ipn + 2];
            }
        }

        // ---- GEMM1: D1[16 edges][128 hid] ----
        f32x4 acc[8];
#pragma unroll
        for (int nt = 0; nt < 8; ++nt) acc[nt] = (f32x4){0.f, 0.f, 0.f, 0.f};
#pragma unroll
        for (int kt = 0; kt < 3; ++kt) {
            bf16x8 a = *(bf16x8*)&EPw[wv][kt][lane][0];
#pragma unroll
            for (int nt = 0; nt < 8; ++nt) {
                bf16x8 bfr = *(bf16x8*)&W1F[kt][nt][lane][0];
                acc[nt] = __builtin_amdgcn_mfma_f32_16x16x32_bf16(a, bfr, acc[nt], 0, 0, 0);
            }
        }

        // ---- bias + LN (16-lane groups) ----
        float s1[4] = {0,0,0,0}, s2[4] = {0,0,0,0};
#pragma unroll
        for (int nt = 0; nt < 8; ++nt)
#pragma unroll
            for (int r = 0; r < 4; ++r) {
                float x = acc[nt][r] + b1v[nt];
                s1[r] += x; s2[r] += x * x;
            }
#pragma unroll
        for (int r = 0; r < 4; ++r) {
#pragma unroll
            for (int off = 1; off < 16; off <<= 1) {
                s1[r] += __shfl_xor(s1[r], off, 64);
                s2[r] += __shfl_xor(s2[r], off, 64);
            }
        }
        float mu[4], rs[4];
#pragma unroll
        for (int r = 0; r < 4; ++r) {
            mu[r] = s1[r] * (1.0f / HID);
            float var = s2[r] * (1.0f / HID) - mu[r] * mu[r];
            rs[r] = rsqrtf(var + 1e-5f);
        }

        // ---- GELU + pack into A-frag layout (P over EPw[wv]) ----
#pragma unroll
        for (int nt = 0; nt < 8; ++nt) {
            int kt2 = nt >> 1;
            int q2  = (nt * 2 + (n16 >> 3)) & 3;
            int jj  = n16 & 7;
#pragma unroll
            for (int r = 0; r < 4; ++r) {
                float x  = acc[nt][r] + b1v[nt];
                float xn = (x - mu[r]) * rs[r] * g1v[nt] + bev[nt];
                EPw[wv][kt2][quad * 4 + r + 16 * q2][jj] = (u16)f2b(gelu_t(xn));
            }
        }

        // ---- GEMM2: D2[16 edges][64 out] ----
        f32x4 acc2[4];
#pragma unroll
        for (int nt2 = 0; nt2 < 4; ++nt2) acc2[nt2] = (f32x4){0.f, 0.f, 0.f, 0.f};
#pragma unroll
        for (int kt2 = 0; kt2 < 4; ++kt2) {
            bf16x8 a2 = *(bf16x8*)&EPw[wv][kt2][lane][0];
#pragma unroll
            for (int nt2 = 0; nt2 < 4; ++nt2) {
                bf16x8 bfr2 = *(bf16x8*)&W2F[kt2][nt2][lane][0];
                acc2[nt2] = __builtin_amdgcn_mfma_f32_16x16x32_bf16(a2, bfr2, acc2[nt2], 0, 0, 0);
            }
        }

        // ---- mean over 16 edges (+b2) -> meansh ----
#pragma unroll
        for (int nt2 = 0; nt2 < 4; ++nt2) {
            float cs = acc2[nt2][0] + acc2[nt2][1] + acc2[nt2][2] + acc2[nt2][3];
            cs += __shfl_xor(cs, 16, 64);
            cs += __shfl_xor(cs, 32, 64);
            if (quad == 0) {
                int o = nt2 * 16 + n16;
                meansh[wv * 4 + pp][o] = cs * (1.0f / KNN) + b2s[o];
            }
        }
    }

    // ======== phase 2: point MLP (MFMA) for the block's 32 points ========
    __syncthreads();   // all means written; safe to overlay W1F/W2F/biases

    for (int s = tid; s < 2 * 8 * 64; s += 512) {   // Wo1 B-frags (K=64)
        int kt = s >> 9, nt = (s >> 6) & 7, ln = s & 63;
        int q = ln >> 4, nn = ln & 15;
        int col = nt * 16 + nn;
        union { bf16x8 v; unsigned u[4]; } pk;
#pragma unroll
        for (int jj = 0; jj < 4; ++jj) {
            int k0 = kt * 32 + q * 8 + jj * 2;
            pk.u[jj] = pk2(Wo1[(size_t)k0 * HID + col],
                           Wo1[(size_t)(k0 + 1) * HID + col]);
        }
        *(bf16x8*)&W1F[kt][nt][ln][0] = pk.v;
    }
    for (int s = tid; s < 4 * 4 * 64; s += 512) {   // Wo2 B-frags
        int kt2 = s >> 8, nt2 = (s >> 6) & 3, ln = s & 63;
        int q = ln >> 4, nn = ln & 15;
        int o = nt2 * 16 + nn;
        union { bf16x8 v; unsigned u[4]; } pk;
#pragma unroll
        for (int jj = 0; jj < 4; ++jj) {
            int k0 = kt2 * 32 + q * 8 + jj * 2;
            pk.u[jj] = pk2(Wo2[(size_t)k0 * COUT + o],
                           Wo2[(size_t)(k0 + 1) * COUT + o]);
        }
        *(bf16x8*)&W2F[kt2][nt2][ln][0] = pk.v;
    }
    if (tid < HID) { b1s[tid] = bo1[tid]; g1s[tid] = go_[tid]; be1s[tid] = beo[tid]; }
    if (tid >= HID && tid < HID + COUT) b2s[tid - HID] = bo2[tid - HID];
    __syncthreads();

    if (wv < 2) {   // wave 0: points 0-15; wave 1: points 16-31
        const int pr0 = wv * 16;
        bf16x8 af[2];
#pragma unroll
        for (int kt = 0; kt < 2; ++kt) {
            const float* mrow = &meansh[pr0 + n16][kt * 32 + quad * 8];
            float4 A = *(const float4*)mrow, B4 = *(const float4*)(mrow + 4);
            union { bf16x8 v; unsigned u[4]; } pk;
            pk.u[0] = pk2(A.x, A.y); pk.u[1] = pk2(A.z, A.w);
            pk.u[2] = pk2(B4.x, B4.y); pk.u[3] = pk2(B4.z, B4.w);
            af[kt] = pk.v;
        }

        f32x4 acc[8];
#pragma unroll
        for (int nt = 0; nt < 8; ++nt) acc[nt] = (f32x4){0.f, 0.f, 0.f, 0.f};
#pragma unroll
        for (int kt = 0; kt < 2; ++kt)
#pragma unroll
            for (int nt = 0; nt < 8; ++nt) {
                bf16x8 bfr = *(bf16x8*)&W1F[kt][nt][lane][0];
                acc[nt] = __builtin_amdgcn_mfma_f32_16x16x32_bf16(af[kt], bfr, acc[nt], 0, 0, 0);
            }

        float pb1[8], pg1[8], pbe[8];
#pragma unroll
        for (int nt = 0; nt < 8; ++nt) {
            pb1[nt] = b1s[nt * 16 + n16];
            pg1[nt] = g1s[nt * 16 + n16];
            pbe[nt] = be1s[nt * 16 + n16];
        }
        float s1[4] = {0,0,0,0}, s2[4] = {0,0,0,0};
#pragma unroll
        for (int nt = 0; nt < 8; ++nt)
#pragma unroll
            for (int r = 0; r < 4; ++r) {
                float x = acc[nt][r] + pb1[nt];
                s1[r] += x; s2[r] += x * x;
            }
#pragma unroll
        for (int r = 0; r < 4; ++r) {
#pragma unroll
            for (int off = 1; off < 16; off <<= 1) {
                s1[r] += __shfl_xor(s1[r], off, 64);
                s2[r] += __shfl_xor(s2[r], off, 64);
            }
        }
#pragma unroll
        for (int nt = 0; nt < 8; ++nt) {
            int kt2 = nt >> 1;
            int q2  = (nt * 2 + (n16 >> 3)) & 3;
            int jj  = n16 & 7;
#pragma unroll
            for (int r = 0; r < 4; ++r) {
                float mu = s1[r] * (1.0f / HID);
                float var = s2[r] * (1.0f / HID) - mu * mu;
                float rs = rsqrtf(var + 1e-5f);
                float x  = acc[nt][r] + pb1[nt];
                float xn = (x - mu) * rs * pg1[nt] + pbe[nt];
                EPw[wv][kt2][quad * 4 + r + 16 * q2][jj] = (u16)f2b(gelu_t(xn));
            }
        }

        f32x4 acc2[4];
#pragma unroll
        for (int nt2 = 0; nt2 < 4; ++nt2) acc2[nt2] = (f32x4){0.f, 0.f, 0.f, 0.f};
#pragma unroll
        for (int kt2 = 0; kt2 < 4; ++kt2) {
            bf16x8 a2 = *(bf16x8*)&EPw[wv][kt2][lane][0];
#pragma unroll
            for (int nt2 = 0; nt2 < 4; ++nt2) {
                bf16x8 bfr2 = *(bf16x8*)&W2F[kt2][nt2][lane][0];
                acc2[nt2] = __builtin_amdgcn_mfma_f32_16x16x32_bf16(a2, bfr2, acc2[nt2], 0, 0, 0);
            }
        }

        // stage final rows into meansh (means fully consumed by af above;
        // cross-wave rows are disjoint: wave w writes rows [16w,16w+16))
#pragma unroll
        for (int nt2 = 0; nt2 < 4; ++nt2) {
            int o = nt2 * 16 + n16;
#pragma unroll
            for (int r = 0; r < 4; ++r)
                meansh[pr0 + quad * 4 + r][o] = acc2[nt2][r] + b2s[o];
        }
    }
    __syncthreads();

    // coalesced float4 store: thread -> (point = tid>>4, 4 channels)
    {
        int p = tid >> 4, c = (tid & 15) * 4;
        float4 v = *(const float4*)&meansh[p][c];
        *(float4*)&out[(size_t)(ptb + p) * 64 + c] = v;
    }
}

extern "C" void kernel_launch(void* const* d_in, const int* in_sizes, int n_in,
                              void* d_out, int out_size, void* d_ws, size_t ws_size,
                              hipStream_t stream) {
    const float* verts = (const float*)d_in[0];
    const float* feats = (const float*)d_in[1];
    const float* W1  = (const float*)d_in[2];
    const float* b1  = (const float*)d_in[3];
    const float* g1  = (const float*)d_in[4];
    const float* be1 = (const float*)d_in[5];
    const float* W2  = (const float*)d_in[6];
    const float* b2  = (const float*)d_in[7];
    const float* Wo1 = (const float*)d_in[8];
    const float* bo1 = (const float*)d_in[9];
    const float* go_ = (const float*)d_in[10];
    const float* beo = (const float*)d_in[11];
    const float* Wo2 = (const float*)d_in[12];
    const float* bo2 = (const float*)d_in[13];
    float* out = (float*)d_out;

    (void)in_sizes; (void)n_in; (void)out_size;

    const size_t pv_bytes = (size_t)BATCH * NPTS * sizeof(float4);  // 256 KB
    const size_t bf_bytes = (size_t)BATCH * NPTS * 32;              // 512 KB
    if (ws_size >= pv_bytes + bf_bytes) {
        float4* pv = (float4*)d_ws;
        uint4*  bf = (uint4*)((char*)d_ws + pv_bytes);
        prep2_kernel<<<(BATCH * NPTS + 255) / 256, 256, 0, stream>>>(verts, pv, bf);
        knn14_kernel<<<(BATCH * NPTS) / 32, 512, 0, stream>>>(pv, bf, (int*)out);
    } else if (ws_size >= pv_bytes) {
        float4* pv = (float4*)d_ws;
        prep_kernel<<<(BATCH * NPTS + 255) / 256, 256, 0, stream>>>(verts, pv);
        knn9_kernel<<<(BATCH * NPTS) / 8, 256, 0, stream>>>(pv, (int*)out);
    } else {
        knn_kernel<<<(BATCH * NPTS) / 4, 256, 0, stream>>>(verts, (int*)out);
    }
    edge8_kernel<<<(BATCH * NPTS) / 32, 512, 0, stream>>>(
        verts, feats, W1, b1, g1, be1, W2, b2,
        Wo1, bo1, go_, beo, Wo2, bo2, out);
}

// Round 12
// 185.266 us; speedup vs baseline: 2.1018x; 2.1018x over previous
//
#include <hip/hip_runtime.h>
#include <hip/hip_bf16.h>
#include <math.h>

#define BATCH 2
#define NPTS  8192
#define CIN   32
#define HID   128
#define COUT  64
#define EIN   67
#define KNN   16

#define TILE  1024     // fallback knn candidate tile
#define CAP   128      // survivor cap per point
#define KMARGIN 1e-3f  // scalar-path filter margin (exact f both passes)
#define KM_MFMA 4e-3f  // mfma-path margin: covers 2*eps, eps<=1.4e-3 (split-bf16)

typedef unsigned short u16;
typedef unsigned long long u64;
typedef __attribute__((ext_vector_type(8))) short bf16x8;  // MFMA A/B frag
typedef __attribute__((ext_vector_type(4))) float f32x4;   // MFMA C/D frag

#if defined(__has_builtin)
#if __has_builtin(__builtin_amdgcn_rcpf)
#define USE_RCPF 1
#endif
#endif

__device__ __forceinline__ u16 f2b(float f) {   // RNE fp32->bf16
    unsigned u = __float_as_uint(f);
    return (u16)((u + 0x7FFFu + ((u >> 16) & 1u)) >> 16);
}
__device__ __forceinline__ float b2f(u16 h) {
    return __uint_as_float(((unsigned)h) << 16);
}
__device__ __forceinline__ unsigned pk2(float a, float b) {
    return (unsigned)f2b(a) | ((unsigned)f2b(b) << 16);
}
__device__ __forceinline__ float gelu_t(float x) {
    // tanh-approx GELU via x * e^u/(e^u+1), u = 1.59577(x + 0.044715 x^3)
    float u = 1.5957691216057308f * (x + 0.044715f * x * x * x);
    float ex = __expf(u);
#ifdef USE_RCPF
    return x * ex * __builtin_amdgcn_rcpf(ex + 1.0f);
#else
    return x * ex / (ex + 1.0f);
#endif
}

// 16th-smallest (rank-15 ascending, ties counted) of 64 per-lane values via
// bitonic sort on shuffles (HW-green in knn9/knn11/knn12).
__device__ __forceinline__ float rank16_of_64(float v, int lane) {
#pragma unroll
    for (int k = 2; k <= 64; k <<= 1) {
#pragma unroll
        for (int j = k >> 1; j > 0; j >>= 1) {
            float o = __shfl_xor(v, j, 64);
            bool lower = (lane & j) == 0;
            bool asc   = (lane & k) == 0;   // k=64: ascending everywhere
            float mn = fminf(v, o), mx = fmaxf(v, o);
            v = (lower == asc) ? mn : mx;
        }
    }
    return __shfl(v, 15, 64);
}

// ============== prep: verts -> pv {x,y,z,sq} ==============
__global__ void prep_kernel(const float* __restrict__ verts, float4* __restrict__ pv) {
    int i = blockIdx.x * blockDim.x + threadIdx.x;
    if (i >= BATCH * NPTS) return;
    float x = verts[3 * i], y = verts[3 * i + 1], z = verts[3 * i + 2];
    float sq = __fadd_rn(__fadd_rn(__fmul_rn(x, x), __fmul_rn(y, y)), __fmul_rn(z, z));
    pv[i] = make_float4(x, y, z, sq);
}

// ============== prep2: pv + candidate B-fragments (split-bf16, 32B/cand) ====
// (HW-verified by knn11/knn12 green runs.)
__global__ void prep2_kernel(const float* __restrict__ verts,
                             float4* __restrict__ pv, uint4* __restrict__ bfrag) {
    int i = blockIdx.x * blockDim.x + threadIdx.x;
    if (i >= BATCH * NPTS) return;
    float x = verts[3 * i], y = verts[3 * i + 1], z = verts[3 * i + 2];
    float sq = __fadd_rn(__fadd_rn(__fmul_rn(x, x), __fmul_rn(y, y)), __fmul_rn(z, z));
    pv[i] = make_float4(x, y, z, sq);

    u16 xh = f2b(x);  u16 xl = f2b(x - b2f(xh));
    u16 yh = f2b(y);  u16 yl = f2b(y - b2f(yh));
    u16 zh = f2b(z);  u16 zl = f2b(z - b2f(zh));
    u16 ch = f2b(sq); u16 cl = f2b(sq - b2f(ch));

    uint4 lo, hi;
    lo.x = (unsigned)xh | ((unsigned)xl << 16);   // k0,k1
    lo.y = (unsigned)xh | ((unsigned)yh << 16);   // k2,k3
    lo.z = (unsigned)yl | ((unsigned)yh << 16);   // k4,k5
    lo.w = (unsigned)zh | ((unsigned)zl << 16);   // k6,k7
    hi.x = (unsigned)zh | ((unsigned)ch << 16);   // k8,k9
    hi.y = (unsigned)cl;                          // k10,k11=0
    hi.z = 0u; hi.w = 0u;                         // k12..15 = 0 (A zero there too)
    bfrag[(size_t)i * 2]     = lo;
    bfrag[(size_t)i * 2 + 1] = hi;
}

// ============== KNN v12 (green, r7/r10): MFMA filter, 8 waves + unroll-2 ====
__global__ __launch_bounds__(512, 8) void knn12_kernel(const float4* __restrict__ pv,
                                                       const uint4* __restrict__ bfrag,
                                                       int* __restrict__ nbr_out_rows) {
    __shared__ float mnsh[8][16][17];    // 8.5 KB bin-mins (pad 17)
    __shared__ float taus[16];
    __shared__ int   cnt[16];
    __shared__ int   sJ[16][CAP];        // 8 KB survivor indices
    __shared__ float bufD[16][CAP];      // 8 KB exact distances (rescore)

    const int tid = threadIdx.x, lane = tid & 63, wv = tid >> 6;   // wv 0..7
    const int col = lane & 15, qq = lane >> 4;
    const int ptb = blockIdx.x * 16;
    const int b = ptb >> 13, i0 = ptb & (NPTS - 1);
    const float4* __restrict__ P = pv + (size_t)b * NPTS;
    const uint4* __restrict__ BF = bfrag + (size_t)b * NPTS * 2;

    union U { uint4 u; bf16x8 v; };

    union { bf16x8 v; unsigned w[4]; } A;
    {
        float4 s = P[i0 + col];
        float mx = -2.0f * s.x, my = -2.0f * s.y, mz = -2.0f * s.z;
        u16 mxh = f2b(mx); u16 mxl = f2b(mx - b2f(mxh));
        u16 myh = f2b(my); u16 myl = f2b(my - b2f(myh));
        u16 mzh = f2b(mz); u16 mzl = f2b(mz - b2f(mzh));
        if (qq == 0) {
            A.w[0] = (unsigned)mxh | ((unsigned)mxh << 16);   // k0,k1
            A.w[1] = (unsigned)mxl | ((unsigned)myh << 16);   // k2,k3
            A.w[2] = (unsigned)myh | ((unsigned)myl << 16);   // k4,k5
            A.w[3] = (unsigned)mzh | ((unsigned)mzh << 16);   // k6,k7
        } else if (qq == 1) {
            A.w[0] = (unsigned)mzl | (0x3F80u << 16);         // k8, k9=1.0
            A.w[1] = 0x3F80u;                                 // k10=1.0, k11=0
            A.w[2] = 0u; A.w[3] = 0u;
        } else {
            A.w[0] = A.w[1] = A.w[2] = A.w[3] = 0u;           // k16..31 = 0
        }
    }

    const int cb = wv * 1024;   // this wave's candidate eighth
    const uint4* __restrict__ bp = BF + ((size_t)(cb + col) * 2 + (qq & 1));

    float mn0 = INFINITY, mn1 = INFINITY, mn2 = INFINITY, mn3 = INFINITY;
    for (int t = 0; t < 32; t += 2) {
        U b0, b1;
        b0.u = bp[(size_t)t * 32];
        b1.u = bp[(size_t)(t + 1) * 32];
        f32x4 a0 = (f32x4){0.f, 0.f, 0.f, 0.f};
        f32x4 a1 = (f32x4){0.f, 0.f, 0.f, 0.f};
        a0 = __builtin_amdgcn_mfma_f32_16x16x32_bf16(A.v, b0.v, a0, 0, 0, 0);
        a1 = __builtin_amdgcn_mfma_f32_16x16x32_bf16(A.v, b1.v, a1, 0, 0, 0);
        mn0 = fminf(mn0, fminf(a0[0], a1[0]));
        mn1 = fminf(mn1, fminf(a0[1], a1[1]));
        mn2 = fminf(mn2, fminf(a0[2], a1[2]));
        mn3 = fminf(mn3, fminf(a0[3], a1[3]));
    }
    mnsh[wv][qq * 4 + 0][col] = mn0;
    mnsh[wv][qq * 4 + 1][col] = mn1;
    mnsh[wv][qq * 4 + 2][col] = mn2;
    mnsh[wv][qq * 4 + 3][col] = mn3;
    if (tid < 16) cnt[tid] = 0;
    __syncthreads();

    {
        float tq[2];
#pragma unroll
        for (int q = 0; q < 2; ++q) {
            const int p = wv * 2 + q;
            float v = fminf(mnsh[lane >> 4][p][lane & 15],
                            mnsh[(lane >> 4) + 4][p][lane & 15]);
            tq[q] = rank16_of_64(v, lane) + KM_MFMA;
        }
        if (lane == 0) { taus[wv * 2] = tq[0]; taus[wv * 2 + 1] = tq[1]; }
    }
    __syncthreads();

    float mytau[4];
#pragma unroll
    for (int r = 0; r < 4; ++r) mytau[r] = taus[qq * 4 + r];   // D row = qq*4+r

    for (int t = 0; t < 64; t += 2) {
        U b0, b1;
        b0.u = bp[(size_t)t * 32];
        b1.u = bp[(size_t)(t + 1) * 32];
        f32x4 a0 = (f32x4){0.f, 0.f, 0.f, 0.f};
        f32x4 a1 = (f32x4){0.f, 0.f, 0.f, 0.f};
        a0 = __builtin_amdgcn_mfma_f32_16x16x32_bf16(A.v, b0.v, a0, 0, 0, 0);
        a1 = __builtin_amdgcn_mfma_f32_16x16x32_bf16(A.v, b1.v, a1, 0, 0, 0);
        const int c0 = cb + t * 16 + col, c1 = c0 + 16;
        if ((a0[0] <= mytau[0]) | (a0[1] <= mytau[1]) |
            (a0[2] <= mytau[2]) | (a0[3] <= mytau[3]) |
            (a1[0] <= mytau[0]) | (a1[1] <= mytau[1]) |
            (a1[2] <= mytau[2]) | (a1[3] <= mytau[3])) {
#pragma unroll
            for (int r = 0; r < 4; ++r) {
                if (a0[r] <= mytau[r]) {
                    int p = qq * 4 + r;
                    int pos = atomicAdd(&cnt[p], 1);
                    if (pos < CAP) sJ[p][pos] = c0;
                }
                if (a1[r] <= mytau[r]) {
                    int p = qq * 4 + r;
                    int pos = atomicAdd(&cnt[p], 1);
                    if (pos < CAP) sJ[p][pos] = c1;
                }
            }
        }
    }
    __syncthreads();

#pragma unroll
    for (int q = 0; q < 2; ++q) {
        const int p = wv * 2 + q;
        int ns = cnt[p]; ns = (ns > CAP) ? CAP : ns;   // >= 16 guaranteed
        const float4 sp = P[i0 + p];
        float dl[2]; int jl[2];
#pragma unroll
        for (int slot = 0; slot < 2; ++slot) {
            int sidx = slot * 64 + lane;
            bool act = sidx < ns;
            int js = act ? sJ[p][sidx] : 0;
            float4 cc = P[js];
            float dot = __fmul_rn(sp.x, cc.x);
            dot = __fmaf_rn(sp.y, cc.y, dot);
            dot = __fmaf_rn(sp.z, cc.z, dot);
            float d = __fsub_rn(__fadd_rn(sp.w, cc.w), __fmul_rn(2.0f, dot));
            if (act) bufD[p][sidx] = d;
            dl[slot] = d; jl[slot] = js;
        }
        int r0 = 0, r1 = 0;
        for (int mm = 0; mm < ns; ++mm) {
            float dm = bufD[p][mm]; int jm = sJ[p][mm];
            r0 += (dm < dl[0]) || (dm == dl[0] && jm < jl[0]);
            r1 += (dm < dl[1]) || (dm == dl[1] && jm < jl[1]);
        }
        if (lane < ns && r0 < KNN)
            nbr_out_rows[(size_t)(ptb + p) * 64 + r0] = jl[0];
        if (64 + lane < ns && r1 < KNN)
            nbr_out_rows[(size_t)(ptb + p) * 64 + r1] = jl[1];
    }
}

// ============== KNN v9 (green 77us): mid fallback if ws < 768KB ==============
__global__ __launch_bounds__(256, 8) void knn9_kernel(const float4* __restrict__ pv,
                                                      int* __restrict__ nbr_out_rows) {
    __shared__ float  bufD[4][2][CAP];
    __shared__ int    bufJ[4][2][CAP];

    const int tid = threadIdx.x, lane = tid & 63, wv = tid >> 6;
    const int pt0 = (blockIdx.x * 4 + wv) * 2;
    const int b = pt0 >> 13, i0 = pt0 & (NPTS - 1);
    const float4* P = pv + (size_t)b * NPTS;

    float4 sp[2];
    float ax[2], ay[2], az[2];
#pragma unroll
    for (int p = 0; p < 2; ++p) {
        sp[p] = P[i0 + p];
        ax[p] = -2.0f * sp[p].x; ay[p] = -2.0f * sp[p].y; az[p] = -2.0f * sp[p].z;
    }

    float mn[2] = {INFINITY, INFINITY};
    for (int t = 0; t < 16; ++t) {
        float4 c0 = P[t * 256 + lane];
        float4 c1 = P[t * 256 + 64 + lane];
        float4 c2 = P[t * 256 + 128 + lane];
        float4 c3 = P[t * 256 + 192 + lane];
#pragma unroll
        for (int p = 0; p < 2; ++p) {
            float f0 = __fmaf_rn(ax[p], c0.x, __fmaf_rn(ay[p], c0.y, __fmaf_rn(az[p], c0.z, c0.w)));
            float f1 = __fmaf_rn(ax[p], c1.x, __fmaf_rn(ay[p], c1.y, __fmaf_rn(az[p], c1.z, c1.w)));
            float f2 = __fmaf_rn(ax[p], c2.x, __fmaf_rn(ay[p], c2.y, __fmaf_rn(az[p], c2.z, c2.w)));
            float f3 = __fmaf_rn(ax[p], c3.x, __fmaf_rn(ay[p], c3.y, __fmaf_rn(az[p], c3.z, c3.w)));
            mn[p] = fminf(fminf(fminf(mn[p], f0), fminf(f1, f2)), f3);
        }
    }

    float tau[2];
#pragma unroll
    for (int p = 0; p < 2; ++p)
        tau[p] = rank16_of_64(mn[p], lane) + KMARGIN;

    int base[2] = {0, 0};
    for (int t = 0; t < 32; ++t) {
        float4 c[4];
#pragma unroll
        for (int k = 0; k < 4; ++k) c[k] = P[t * 256 + k * 64 + lane];
        bool pr[4][2];
        bool anyl = false;
#pragma unroll
        for (int k = 0; k < 4; ++k)
#pragma unroll
            for (int p = 0; p < 2; ++p) {
                float f = __fmaf_rn(ax[p], c[k].x,
                          __fmaf_rn(ay[p], c[k].y,
                          __fmaf_rn(az[p], c[k].z, c[k].w)));
                pr[k][p] = (f <= tau[p]);
                anyl |= pr[k][p];
            }
        if (__ballot(anyl) == 0ull) continue;
#pragma unroll
        for (int k = 0; k < 4; ++k) {
            u64 anyk = __ballot(pr[k][0] | pr[k][1]);
            if (anyk == 0ull) continue;
            int j = t * 256 + k * 64 + lane;
#pragma unroll
            for (int p = 0; p < 2; ++p) {
                u64 mk = __ballot(pr[k][p]);
                if (mk != 0ull) {
                    if (pr[k][p]) {
                        int pos = base[p] + (int)__popcll(mk & ((1ull << lane) - 1ull));
                        if (pos < CAP) bufJ[wv][p][pos] = j;
                    }
                    base[p] += (int)__popcll(mk);
                }
            }
        }
    }

#pragma unroll
    for (int p = 0; p < 2; ++p) {
        int ns = base[p]; ns = (ns > CAP) ? CAP : ns;
        float dloc[2]; int jloc[2];
#pragma unroll
        for (int slot = 0; slot < 2; ++slot) {
            int sidx = slot * 64 + lane;
            bool act = sidx < ns;
            int js = act ? bufJ[wv][p][sidx] : 0;
            float4 cc = P[js];
            float dot = __fmul_rn(sp[p].x, cc.x);
            dot = __fmaf_rn(sp[p].y, cc.y, dot);
            dot = __fmaf_rn(sp[p].z, cc.z, dot);
            float d = __fsub_rn(__fadd_rn(sp[p].w, cc.w), __fmul_rn(2.0f, dot));
            if (act) bufD[wv][p][sidx] = d;
            dloc[slot] = d; jloc[slot] = js;
        }
        int r0 = 0, r1 = 0;
        for (int mm = 0; mm < ns; ++mm) {
            float dm = bufD[wv][p][mm]; int jm = bufJ[wv][p][mm];
            r0 += (dm < dloc[0]) || (dm == dloc[0] && jm < jloc[0]);
            r1 += (dm < dloc[1]) || (dm == dloc[1] && jm < jloc[1]);
        }
        if (lane < ns && r0 < KNN)
            nbr_out_rows[(size_t)(pt0 + p) * 64 + r0] = jloc[0];
        if (64 + lane < ns && r1 < KNN)
            nbr_out_rows[(size_t)(pt0 + p) * 64 + r1] = jloc[1];
    }
}

// ============== KNN fallback (used only if ws too small) ==============
__global__ __launch_bounds__(256) void knn_kernel(const float* __restrict__ verts,
                                                  int* nbr_out_rows) {
    __shared__ float4 tilebuf[TILE];
    __shared__ float  bufD[4][CAP];
    __shared__ int    bufJ[4][CAP];

    const int tid = threadIdx.x, lane = tid & 63, wv = tid >> 6;
    const int pt = blockIdx.x * 4 + wv;
    const int b = pt >> 13, i = pt & (NPTS - 1);
    const float* vb = verts + (size_t)b * NPTS * 3;

    const float xi = vb[3 * i], yi = vb[3 * i + 1], zi = vb[3 * i + 2];
    const float sqi = __fadd_rn(__fadd_rn(__fmul_rn(xi, xi), __fmul_rn(yi, yi)),
                                __fmul_rn(zi, zi));

    float m_d = INFINITY;
    for (int t = 0; t < NPTS / TILE; ++t) {
        __syncthreads();
        for (int s = 0; s < TILE / 256; ++s) {
            int p = t * TILE + s * 256 + tid;
            float px = vb[3 * p], py = vb[3 * p + 1], pz = vb[3 * p + 2];
            float sq = __fadd_rn(__fadd_rn(__fmul_rn(px, px), __fmul_rn(py, py)),
                                 __fmul_rn(pz, pz));
            tilebuf[s * 256 + tid] = make_float4(px, py, pz, sq);
        }
        __syncthreads();
        for (int it = 0; it < TILE / 64; ++it) {
            float4 c = tilebuf[it * 64 + lane];
            float dot = __fmul_rn(xi, c.x);
            dot = __fmaf_rn(yi, c.y, dot);
            dot = __fmaf_rn(zi, c.z, dot);
            float d = __fsub_rn(__fadd_rn(sqi, c.w), __fmul_rn(2.0f, dot));
            m_d = fminf(m_d, d);
        }
    }
    __shared__ float minv[4][64];
    minv[wv][lane] = m_d;
    __syncthreads();
    int rnk = 0;
    for (int mm = 0; mm < 64; ++mm) {
        float vm = minv[wv][mm];
        rnk += (vm < m_d) || (vm == m_d && mm < lane);
    }
    u64 bal = __ballot(rnk == 15);
    float tau = __shfl(m_d, __ffsll(bal) - 1, 64);

    int base = 0;
    for (int t = 0; t < NPTS / TILE; ++t) {
        __syncthreads();
        for (int s = 0; s < TILE / 256; ++s) {
            int p = t * TILE + s * 256 + tid;
            float px = vb[3 * p], py = vb[3 * p + 1], pz = vb[3 * p + 2];
            float sq = __fadd_rn(__fadd_rn(__fmul_rn(px, px), __fmul_rn(py, py)),
                                 __fmul_rn(pz, pz));
            tilebuf[s * 256 + tid] = make_float4(px, py, pz, sq);
        }
        __syncthreads();
        for (int it = 0; it < TILE / 64; ++it) {
            int jl = it * 64 + lane;
            float4 c = tilebuf[jl];
            float dot = __fmul_rn(xi, c.x);
            dot = __fmaf_rn(yi, c.y, dot);
            dot = __fmaf_rn(zi, c.z, dot);
            float d = __fsub_rn(__fadd_rn(sqi, c.w), __fmul_rn(2.0f, dot));
            bool pred = (d <= tau);
            u64 mask = __ballot(pred);
            if (pred) {
                int pos = base + (int)__popcll(mask & ((1ull << lane) - 1ull));
                if (pos < CAP) { bufD[wv][pos] = d; bufJ[wv][pos] = t * TILE + jl; }
            }
            base += (int)__popcll(mask);
        }
    }
    int ns = (base > CAP) ? CAP : base;
    __syncthreads();
#pragma unroll
    for (int slot = 0; slot < 2; ++slot) {
        int sidx = slot * 64 + lane;
        if (sidx < ns) {
            float ds = bufD[wv][sidx];
            int   js = bufJ[wv][sidx];
            int rank = 0;
            for (int mm = 0; mm < ns; ++mm) {
                float dm = bufD[wv][mm];
                int   jm = bufJ[wv][mm];
                rank += (dm < ds) || (dm == ds && jm < js);
            }
            if (rank < KNN) nbr_out_rows[(size_t)pt * 64 + rank] = js;
        }
    }
}

// ============ edge8 v3 (green, r10): W2F in LDS + gather prefetch ============
__global__ __launch_bounds__(512, 2) void edge8_kernel(
    const float* __restrict__ verts, const float* __restrict__ feats,
    const float* __restrict__ W1, const float* __restrict__ b1,
    const float* __restrict__ g1, const float* __restrict__ be1,
    const float* __restrict__ W2, const float* __restrict__ b2,
    const float* __restrict__ Wo1, const float* __restrict__ bo1,
    const float* __restrict__ go_, const float* __restrict__ beo,
    const float* __restrict__ Wo2, const float* __restrict__ bo2,
    float* out)   // rows hold knn idx on entry; final output on exit
{
    __shared__ u16 EPw[8][4][64][8];    // 32 KB: per-wave E/P A-frag region
    __shared__ u16 W1F[3][8][64][8];    // 24 KB (phase2: Wo1 frags in kt 0..1)
    __shared__ u16 W2F[4][4][64][8];    // 8 KB W2 B-frags (phase2: Wo2)
    __shared__ float b1s[HID], g1s[HID], be1s[HID];
    __shared__ float b2s[COUT];
    __shared__ float meansh[32][68];    // 8.5 KB; phase2: staging for out rows

    const int tid  = threadIdx.x;
    const int lane = tid & 63, wv = tid >> 6;    // wv 0..7
    const int quad = lane >> 4, n16 = lane & 15;

    // ---- stage W1 as B-fragments ----
    for (int s = tid; s < 3 * 8 * 64; s += 512) {
        int kt = s >> 9, nt = (s >> 6) & 7, ln = s & 63;
        int q = ln >> 4, nn = ln & 15;
        int col = nt * 16 + nn;
        union { bf16x8 v; unsigned u[4]; } pk;
#pragma unroll
        for (int jj = 0; jj < 4; ++jj) {
            int k0 = kt * 32 + q * 8 + jj * 2;
            float a  = (k0     < EIN) ? W1[(size_t)k0 * HID + col]       : 0.0f;
            float bq = (k0 + 1 < EIN) ? W1[(size_t)(k0 + 1) * HID + col] : 0.0f;
            pk.u[jj] = pk2(a, bq);
        }
        *(bf16x8*)&W1F[kt][nt][ln][0] = pk.v;
    }
    // ---- stage W2 as B-fragments (cooperative; shared across waves) ----
    for (int s = tid; s < 4 * 4 * 64; s += 512) {
        int kt2 = s >> 8, nt2 = (s >> 6) & 3, ln = s & 63;
        int q = ln >> 4, nn = ln & 15;
        int o = nt2 * 16 + nn;
        union { bf16x8 v; unsigned u[4]; } pk;
#pragma unroll
        for (int jj = 0; jj < 4; ++jj) {
            int k0 = kt2 * 32 + q * 8 + jj * 2;
            pk.u[jj] = pk2(W2[(size_t)k0 * COUT + o],
                           W2[(size_t)(k0 + 1) * COUT + o]);
        }
        *(bf16x8*)&W2F[kt2][nt2][ln][0] = pk.v;
    }
    if (tid < HID) { b1s[tid] = b1[tid]; g1s[tid] = g1[tid]; be1s[tid] = be1[tid]; }
    if (tid >= HID && tid < HID + COUT) b2s[tid - HID] = b2[tid - HID];
    __syncthreads();   // W1F + W2F + biases visible to all waves

    const int ptb = blockIdx.x * 32;
    const int bb  = ptb >> 13;
    const float* fb  = feats + (size_t)bb * NPTS * CIN;
    const float* vbk = verts + (size_t)bb * NPTS * 3;
    const int ptw = ptb + wv * 4;              // this wave's 4 points
    const int ipw = ptw & (NPTS - 1);

    // hoisted LN operands (point-independent)
    float b1v[8], g1v[8], bev[8];
#pragma unroll
    for (int nt = 0; nt < 8; ++nt) {
        b1v[nt] = b1s[nt * 16 + n16];
        g1v[nt] = g1s[nt * 16 + n16];
        bev[nt] = be1s[nt * 16 + n16];
    }

    const int k16 = lane & 15;
    const int qq  = lane >> 4;

    int jnv[4];
#pragma unroll
    for (int pp = 0; pp < 4; ++pp)
        jnv[pp] = ((const int*)out)[(size_t)(ptw + pp) * 64 + k16];

    // ---- preload pp=0 gathers ----
    float4 nA, nB, sA, sB;
    float rx = 0.f, ry = 0.f, rz = 0.f;
    {
        const int jn = jnv[0], ipn = ipw;
        const float* nsrc = fb + (size_t)jn * CIN + qq * 8;
        nA = *(const float4*)nsrc; nB = *(const float4*)(nsrc + 4);
        const float* ssrc = fb + (size_t)ipn * CIN + qq * 8;
        sA = *(const float4*)ssrc; sB = *(const float4*)(ssrc + 4);
        if (qq == 0) {
            rx = vbk[3 * jn]     - vbk[3 * ipn];
            ry = vbk[3 * jn + 1] - vbk[3 * ipn + 1];
            rz = vbk[3 * jn + 2] - vbk[3 * ipn + 2];
        }
    }

#pragma unroll
    for (int pp = 0; pp < 4; ++pp) {
        // ---- pack + store E from prefetched regs (3 b128 per lane) ----
        {
            union { bf16x8 v; unsigned u[4]; } e0, e1, e2;
            e0.u[0] = pk2(nA.x, nA.y); e0.u[1] = pk2(nA.z, nA.w);
            e0.u[2] = pk2(nB.x, nB.y); e0.u[3] = pk2(nB.z, nB.w);
            e1.u[0] = pk2(sA.x, sA.y); e1.u[1] = pk2(sA.z, sA.w);
            e1.u[2] = pk2(sB.x, sB.y); e1.u[3] = pk2(sB.z, sB.w);
            e2.u[0] = e2.u[1] = e2.u[2] = e2.u[3] = 0u;
            if (qq == 0) { e2.u[0] = pk2(rx, ry); e2.u[1] = pk2(rz, 0.0f); }
            *(bf16x8*)&EPw[wv][0][lane][0] = e0.v;
            *(bf16x8*)&EPw[wv][1][lane][0] = e1.v;
            *(bf16x8*)&EPw[wv][2][lane][0] = e2.v;
        }

        // ---- issue NEXT point's gathers; latency hides under compute below ----
        if (pp < 3) {
            const int jn = jnv[pp + 1], ipn = ipw + pp + 1;
            const float* nsrc = fb + (size_t)jn * CIN + qq * 8;
            nA = *(const float4*)nsrc; nB = *(const float4*)(nsrc + 4);
            const float* ssrc = fb + (size_t)ipn * CIN + qq * 8;
            sA = *(const float4*)ssrc; sB = *(const float4*)(ssrc + 4);
            if (qq == 0) {
                rx = vbk[3 * jn]     - vbk[3 * ipn];
                ry = vbk[3 * jn + 1] - vbk[3 * ipn + 1];
                rz = vbk[3 * jn + 2] - vbk[3 * ipn + 2];
            }
        }

        // ---- GEMM1: D1[16 edges][128 hid] ----
        f32x4 acc[8];
#pragma unroll
        for (int nt = 0; nt < 8; ++nt) acc[nt] = (f32x4){0.f, 0.f, 0.f, 0.f};
#pragma unroll
        for (int kt = 0; kt < 3; ++kt) {
            bf16x8 a = *(bf16x8*)&EPw[wv][kt][lane][0];
#pragma unroll
            for (int nt = 0; nt < 8; ++nt) {
                bf16x8 bfr = *(bf16x8*)&W1F[kt][nt][lane][0];
                acc[nt] = __builtin_amdgcn_mfma_f32_16x16x32_bf16(a, bfr, acc[nt], 0, 0, 0);
            }
        }

        // ---- bias + LN (16-lane groups) ----
        float s1[4] = {0,0,0,0}, s2[4] = {0,0,0,0};
#pragma unroll
        for (int nt = 0; nt < 8; ++nt)
#pragma unroll
            for (int r = 0; r < 4; ++r) {
                float x = acc[nt][r] + b1v[nt];
                s1[r] += x; s2[r] += x * x;
            }
#pragma unroll
        for (int r = 0; r < 4; ++r) {
#pragma unroll
            for (int off = 1; off < 16; off <<= 1) {
                s1[r] += __shfl_xor(s1[r], off, 64);
                s2[r] += __shfl_xor(s2[r], off, 64);
            }
        }
        float mu[4], rs[4];
#pragma unroll
        for (int r = 0; r < 4; ++r) {
            mu[r] = s1[r] * (1.0f / HID);
            float var = s2[r] * (1.0f / HID) - mu[r] * mu[r];
            rs[r] = rsqrtf(var + 1e-5f);
        }

        // ---- GELU + pack into A-frag layout (P over EPw[wv]) ----
#pragma unroll
        for (int nt = 0; nt < 8; ++nt) {
            int kt2 = nt >> 1;
            int q2  = (nt * 2 + (n16 >> 3)) & 3;
            int jj  = n16 & 7;
#pragma unroll
            for (int r = 0; r < 4; ++r) {
                float x  = acc[nt][r] + b1v[nt];
                float xn = (x - mu[r]) * rs[r] * g1v[nt] + bev[nt];
                EPw[wv][kt2][quad * 4 + r + 16 * q2][jj] = (u16)f2b(gelu_t(xn));
            }
        }

        // ---- GEMM2: D2[16 edges][64 out] ----
        f32x4 acc2[4];
#pragma unroll
        for (int nt2 = 0; nt2 < 4; ++nt2) acc2[nt2] = (f32x4){0.f, 0.f, 0.f, 0.f};
#pragma unroll
        for (int kt2 = 0; kt2 < 4; ++kt2) {
            bf16x8 a2 = *(bf16x8*)&EPw[wv][kt2][lane][0];
#pragma unroll
            for (int nt2 = 0; nt2 < 4; ++nt2) {
                bf16x8 bfr2 = *(bf16x8*)&W2F[kt2][nt2][lane][0];
                acc2[nt2] = __builtin_amdgcn_mfma_f32_16x16x32_bf16(a2, bfr2, acc2[nt2], 0, 0, 0);
            }
        }

        // ---- mean over 16 edges (+b2) -> meansh ----
#pragma unroll
        for (int nt2 = 0; nt2 < 4; ++nt2) {
            float cs = acc2[nt2][0] + acc2[nt2][1] + acc2[nt2][2] + acc2[nt2][3];
            cs += __shfl_xor(cs, 16, 64);
            cs += __shfl_xor(cs, 32, 64);
            if (quad == 0) {
                int o = nt2 * 16 + n16;
                meansh[wv * 4 + pp][o] = cs * (1.0f / KNN) + b2s[o];
            }
        }
    }

    // ======== phase 2: point MLP (MFMA) for the block's 32 points ========
    __syncthreads();   // all means written; safe to overlay W1F/W2F/biases

    for (int s = tid; s < 2 * 8 * 64; s += 512) {   // Wo1 B-frags (K=64)
        int kt = s >> 9, nt = (s >> 6) & 7, ln = s & 63;
        int q = ln >> 4, nn = ln & 15;
        int col = nt * 16 + nn;
        union { bf16x8 v; unsigned u[4]; } pk;
#pragma unroll
        for (int jj = 0; jj < 4; ++jj) {
            int k0 = kt * 32 + q * 8 + jj * 2;
            pk.u[jj] = pk2(Wo1[(size_t)k0 * HID + col],
                           Wo1[(size_t)(k0 + 1) * HID + col]);
        }
        *(bf16x8*)&W1F[kt][nt][ln][0] = pk.v;
    }
    for (int s = tid; s < 4 * 4 * 64; s += 512) {   // Wo2 B-frags
        int kt2 = s >> 8, nt2 = (s >> 6) & 3, ln = s & 63;
        int q = ln >> 4, nn = ln & 15;
        int o = nt2 * 16 + nn;
        union { bf16x8 v; unsigned u[4]; } pk;
#pragma unroll
        for (int jj = 0; jj < 4; ++jj) {
            int k0 = kt2 * 32 + q * 8 + jj * 2;
            pk.u[jj] = pk2(Wo2[(size_t)k0 * COUT + o],
                           Wo2[(size_t)(k0 + 1) * COUT + o]);
        }
        *(bf16x8*)&W2F[kt2][nt2][ln][0] = pk.v;
    }
    if (tid < HID) { b1s[tid] = bo1[tid]; g1s[tid] = go_[tid]; be1s[tid] = beo[tid]; }
    if (tid >= HID && tid < HID + COUT) b2s[tid - HID] = bo2[tid - HID];
    __syncthreads();

    if (wv < 2) {   // wave 0: points 0-15; wave 1: points 16-31
        const int pr0 = wv * 16;
        bf16x8 af[2];
#pragma unroll
        for (int kt = 0; kt < 2; ++kt) {
            const float* mrow = &meansh[pr0 + n16][kt * 32 + quad * 8];
            float4 A = *(const float4*)mrow, B4 = *(const float4*)(mrow + 4);
            union { bf16x8 v; unsigned u[4]; } pk;
            pk.u[0] = pk2(A.x, A.y); pk.u[1] = pk2(A.z, A.w);
            pk.u[2] = pk2(B4.x, B4.y); pk.u[3] = pk2(B4.z, B4.w);
            af[kt] = pk.v;
        }

        f32x4 acc[8];
#pragma unroll
        for (int nt = 0; nt < 8; ++nt) acc[nt] = (f32x4){0.f, 0.f, 0.f, 0.f};
#pragma unroll
        for (int kt = 0; kt < 2; ++kt)
#pragma unroll
            for (int nt = 0; nt < 8; ++nt) {
                bf16x8 bfr = *(bf16x8*)&W1F[kt][nt][lane][0];
                acc[nt] = __builtin_amdgcn_mfma_f32_16x16x32_bf16(af[kt], bfr, acc[nt], 0, 0, 0);
            }

        float pb1[8], pg1[8], pbe[8];
#pragma unroll
        for (int nt = 0; nt < 8; ++nt) {
            pb1[nt] = b1s[nt * 16 + n16];
            pg1[nt] = g1s[nt * 16 + n16];
            pbe[nt] = be1s[nt * 16 + n16];
        }
        float s1[4] = {0,0,0,0}, s2[4] = {0,0,0,0};
#pragma unroll
        for (int nt = 0; nt < 8; ++nt)
#pragma unroll
            for (int r = 0; r < 4; ++r) {
                float x = acc[nt][r] + pb1[nt];
                s1[r] += x; s2[r] += x * x;
            }
#pragma unroll
        for (int r = 0; r < 4; ++r) {
#pragma unroll
            for (int off = 1; off < 16; off <<= 1) {
                s1[r] += __shfl_xor(s1[r], off, 64);
                s2[r] += __shfl_xor(s2[r], off, 64);
            }
        }
#pragma unroll
        for (int nt = 0; nt < 8; ++nt) {
            int kt2 = nt >> 1;
            int q2  = (nt * 2 + (n16 >> 3)) & 3;
            int jj  = n16 & 7;
#pragma unroll
            for (int r = 0; r < 4; ++r) {
                float mu = s1[r] * (1.0f / HID);
                float var = s2[r] * (1.0f / HID) - mu * mu;
                float rs = rsqrtf(var + 1e-5f);
                float x  = acc[nt][r] + pb1[nt];
                float xn = (x - mu) * rs * pg1[nt] + pbe[nt];
                EPw[wv][kt2][quad * 4 + r + 16 * q2][jj] = (u16)f2b(gelu_t(xn));
            }
        }

        f32x4 acc2[4];
#pragma unroll
        for (int nt2 = 0; nt2 < 4; ++nt2) acc2[nt2] = (f32x4){0.f, 0.f, 0.f, 0.f};
#pragma unroll
        for (int kt2 = 0; kt2 < 4; ++kt2) {
            bf16x8 a2 = *(bf16x8*)&EPw[wv][kt2][lane][0];
#pragma unroll
            for (int nt2 = 0; nt2 < 4; ++nt2) {
                bf16x8 bfr2 = *(bf16x8*)&W2F[kt2][nt2][lane][0];
                acc2[nt2] = __builtin_amdgcn_mfma_f32_16x16x32_bf16(a2, bfr2, acc2[nt2], 0, 0, 0);
            }
        }

        // stage final rows into meansh (means fully consumed by af above;
        // cross-wave rows are disjoint: wave w writes rows [16w,16w+16))
#pragma unroll
        for (int nt2 = 0; nt2 < 4; ++nt2) {
            int o = nt2 * 16 + n16;
#pragma unroll
            for (int r = 0; r < 4; ++r)
                meansh[pr0 + quad * 4 + r][o] = acc2[nt2][r] + b2s[o];
        }
    }
    __syncthreads();

    // coalesced float4 store: thread -> (point = tid>>4, 4 channels)
    {
        int p = tid >> 4, c = (tid & 15) * 4;
        float4 v = *(const float4*)&meansh[p][c];
        *(float4*)&out[(size_t)(ptb + p) * 64 + c] = v;
    }
}

extern "C" void kernel_launch(void* const* d_in, const int* in_sizes, int n_in,
                              void* d_out, int out_size, void* d_ws, size_t ws_size,
                              hipStream_t stream) {
    const float* verts = (const float*)d_in[0];
    const float* feats = (const float*)d_in[1];
    const float* W1  = (const float*)d_in[2];
    const float* b1  = (const float*)d_in[3];
    const float* g1  = (const float*)d_in[4];
    const float* be1 = (const float*)d_in[5];
    const float* W2  = (const float*)d_in[6];
    const float* b2  = (const float*)d_in[7];
    const float* Wo1 = (const float*)d_in[8];
    const float* bo1 = (const float*)d_in[9];
    const float* go_ = (const float*)d_in[10];
    const float* beo = (const float*)d_in[11];
    const float* Wo2 = (const float*)d_in[12];
    const float* bo2 = (const float*)d_in[13];
    float* out = (float*)d_out;

    (void)in_sizes; (void)n_in; (void)out_size;

    const size_t pv_bytes = (size_t)BATCH * NPTS * sizeof(float4);  // 256 KB
    const size_t bf_bytes = (size_t)BATCH * NPTS * 32;              // 512 KB
    if (ws_size >= pv_bytes + bf_bytes) {
        float4* pv = (float4*)d_ws;
        uint4*  bf = (uint4*)((char*)d_ws + pv_bytes);
        prep2_kernel<<<(BATCH * NPTS + 255) / 256, 256, 0, stream>>>(verts, pv, bf);
        knn12_kernel<<<(BATCH * NPTS) / 16, 512, 0, stream>>>(pv, bf, (int*)out);
    } else if (ws_size >= pv_bytes) {
        float4* pv = (float4*)d_ws;
        prep_kernel<<<(BATCH * NPTS + 255) / 256, 256, 0, stream>>>(verts, pv);
        knn9_kernel<<<(BATCH * NPTS) / 8, 256, 0, stream>>>(pv, (int*)out);
    } else {
        knn_kernel<<<(BATCH * NPTS) / 4, 256, 0, stream>>>(verts, (int*)out);
    }
    edge8_kernel<<<(BATCH * NPTS) / 32, 512, 0, stream>>>(
        verts, feats, W1, b1, g1, be1, W2, b2,
        Wo1, bo1, go_, beo, Wo2, bo2, out);
}

// Round 13
// 184.369 us; speedup vs baseline: 2.1121x; 1.0049x over previous
//
#include <hip/hip_runtime.h>
#include <hip/hip_bf16.h>
#include <math.h>

#define BATCH 2
#define NPTS  8192
#define CIN   32
#define HID   128
#define COUT  64
#define EIN   67
#define KNN   16

#define TILE  1024     // fallback knn candidate tile
#define CAP   128      // survivor cap per point
#define KMARGIN 1e-3f  // scalar-path filter margin (exact f both passes)
#define KM_MFMA 4e-3f  // mfma-path margin: covers 2*eps, eps<=1.4e-3 (split-bf16)

typedef unsigned short u16;
typedef unsigned long long u64;
typedef __attribute__((ext_vector_type(8))) short bf16x8;  // MFMA A/B frag
typedef __attribute__((ext_vector_type(4))) float f32x4;   // MFMA C/D frag

#if defined(__has_builtin)
#if __has_builtin(__builtin_amdgcn_rcpf)
#define USE_RCPF 1
#endif
#endif

__device__ __forceinline__ u16 f2b(float f) {   // RNE fp32->bf16
    unsigned u = __float_as_uint(f);
    return (u16)((u + 0x7FFFu + ((u >> 16) & 1u)) >> 16);
}
__device__ __forceinline__ float b2f(u16 h) {
    return __uint_as_float(((unsigned)h) << 16);
}
__device__ __forceinline__ unsigned pk2(float a, float b) {
    return (unsigned)f2b(a) | ((unsigned)f2b(b) << 16);
}
__device__ __forceinline__ float gelu_t(float x) {
    // tanh-approx GELU via x * e^u/(e^u+1), u = 1.59577(x + 0.044715 x^3)
    float u = 1.5957691216057308f * (x + 0.044715f * x * x * x);
    float ex = __expf(u);
#ifdef USE_RCPF
    return x * ex * __builtin_amdgcn_rcpf(ex + 1.0f);
#else
    return x * ex / (ex + 1.0f);
#endif
}

// 16th-smallest (rank-15 ascending, ties counted) of 64 per-lane values via
// bitonic sort on shuffles (HW-green in knn9/knn11/knn12).
__device__ __forceinline__ float rank16_of_64(float v, int lane) {
#pragma unroll
    for (int k = 2; k <= 64; k <<= 1) {
#pragma unroll
        for (int j = k >> 1; j > 0; j >>= 1) {
            float o = __shfl_xor(v, j, 64);
            bool lower = (lane & j) == 0;
            bool asc   = (lane & k) == 0;   // k=64: ascending everywhere
            float mn = fminf(v, o), mx = fmaxf(v, o);
            v = (lower == asc) ? mn : mx;
        }
    }
    return __shfl(v, 15, 64);
}

// ============== prep: verts -> pv {x,y,z,sq} ==============
__global__ void prep_kernel(const float* __restrict__ verts, float4* __restrict__ pv) {
    int i = blockIdx.x * blockDim.x + threadIdx.x;
    if (i >= BATCH * NPTS) return;
    float x = verts[3 * i], y = verts[3 * i + 1], z = verts[3 * i + 2];
    float sq = __fadd_rn(__fadd_rn(__fmul_rn(x, x), __fmul_rn(y, y)), __fmul_rn(z, z));
    pv[i] = make_float4(x, y, z, sq);
}

// ============== prep2: pv + candidate B-fragments (split-bf16, 32B/cand) ====
// (HW-verified by knn11/knn12 green runs.)
__global__ void prep2_kernel(const float* __restrict__ verts,
                             float4* __restrict__ pv, uint4* __restrict__ bfrag) {
    int i = blockIdx.x * blockDim.x + threadIdx.x;
    if (i >= BATCH * NPTS) return;
    float x = verts[3 * i], y = verts[3 * i + 1], z = verts[3 * i + 2];
    float sq = __fadd_rn(__fadd_rn(__fmul_rn(x, x), __fmul_rn(y, y)), __fmul_rn(z, z));
    pv[i] = make_float4(x, y, z, sq);

    u16 xh = f2b(x);  u16 xl = f2b(x - b2f(xh));
    u16 yh = f2b(y);  u16 yl = f2b(y - b2f(yh));
    u16 zh = f2b(z);  u16 zl = f2b(z - b2f(zh));
    u16 ch = f2b(sq); u16 cl = f2b(sq - b2f(ch));

    uint4 lo, hi;
    lo.x = (unsigned)xh | ((unsigned)xl << 16);   // k0,k1
    lo.y = (unsigned)xh | ((unsigned)yh << 16);   // k2,k3
    lo.z = (unsigned)yl | ((unsigned)yh << 16);   // k4,k5
    lo.w = (unsigned)zh | ((unsigned)zl << 16);   // k6,k7
    hi.x = (unsigned)zh | ((unsigned)ch << 16);   // k8,k9
    hi.y = (unsigned)cl;                          // k10,k11=0
    hi.z = 0u; hi.w = 0u;                         // k12..15 = 0 (A zero there too)
    bfrag[(size_t)i * 2]     = lo;
    bfrag[(size_t)i * 2 + 1] = hi;
}

// ============== KNN v12 u4: MFMA filter, 8 waves, unroll-4 ==============
// Identical semantics to the green knn12 (r7/r10/r12); scan loops widened
// from 2 to 4 in-flight B-frag loads for ILP. Live regs ~44-50, well under
// the 64-VGPR ceiling of (512,8) (r12 measured 28 at unroll-2).
__global__ __launch_bounds__(512, 8) void knn12_kernel(const float4* __restrict__ pv,
                                                       const uint4* __restrict__ bfrag,
                                                       int* __restrict__ nbr_out_rows) {
    __shared__ float mnsh[8][16][17];    // 8.5 KB bin-mins (pad 17)
    __shared__ float taus[16];
    __shared__ int   cnt[16];
    __shared__ int   sJ[16][CAP];        // 8 KB survivor indices
    __shared__ float bufD[16][CAP];      // 8 KB exact distances (rescore)

    const int tid = threadIdx.x, lane = tid & 63, wv = tid >> 6;   // wv 0..7
    const int col = lane & 15, qq = lane >> 4;
    const int ptb = blockIdx.x * 16;
    const int b = ptb >> 13, i0 = ptb & (NPTS - 1);
    const float4* __restrict__ P = pv + (size_t)b * NPTS;
    const uint4* __restrict__ BF = bfrag + (size_t)b * NPTS * 2;

    union U { uint4 u; bf16x8 v; };

    union { bf16x8 v; unsigned w[4]; } A;
    {
        float4 s = P[i0 + col];
        float mx = -2.0f * s.x, my = -2.0f * s.y, mz = -2.0f * s.z;
        u16 mxh = f2b(mx); u16 mxl = f2b(mx - b2f(mxh));
        u16 myh = f2b(my); u16 myl = f2b(my - b2f(myh));
        u16 mzh = f2b(mz); u16 mzl = f2b(mz - b2f(mzh));
        if (qq == 0) {
            A.w[0] = (unsigned)mxh | ((unsigned)mxh << 16);   // k0,k1
            A.w[1] = (unsigned)mxl | ((unsigned)myh << 16);   // k2,k3
            A.w[2] = (unsigned)myh | ((unsigned)myl << 16);   // k4,k5
            A.w[3] = (unsigned)mzh | ((unsigned)mzh << 16);   // k6,k7
        } else if (qq == 1) {
            A.w[0] = (unsigned)mzl | (0x3F80u << 16);         // k8, k9=1.0
            A.w[1] = 0x3F80u;                                 // k10=1.0, k11=0
            A.w[2] = 0u; A.w[3] = 0u;
        } else {
            A.w[0] = A.w[1] = A.w[2] = A.w[3] = 0u;           // k16..31 = 0
        }
    }

    const int cb = wv * 1024;   // this wave's candidate eighth
    const uint4* __restrict__ bp = BF + ((size_t)(cb + col) * 2 + (qq & 1));

    float mn0 = INFINITY, mn1 = INFINITY, mn2 = INFINITY, mn3 = INFINITY;
    for (int t = 0; t < 32; t += 4) {
        U b0, b1, b2, b3;
        b0.u = bp[(size_t)t * 32];
        b1.u = bp[(size_t)(t + 1) * 32];
        b2.u = bp[(size_t)(t + 2) * 32];
        b3.u = bp[(size_t)(t + 3) * 32];
        f32x4 a0 = (f32x4){0.f, 0.f, 0.f, 0.f};
        f32x4 a1 = (f32x4){0.f, 0.f, 0.f, 0.f};
        f32x4 a2 = (f32x4){0.f, 0.f, 0.f, 0.f};
        f32x4 a3 = (f32x4){0.f, 0.f, 0.f, 0.f};
        a0 = __builtin_amdgcn_mfma_f32_16x16x32_bf16(A.v, b0.v, a0, 0, 0, 0);
        a1 = __builtin_amdgcn_mfma_f32_16x16x32_bf16(A.v, b1.v, a1, 0, 0, 0);
        a2 = __builtin_amdgcn_mfma_f32_16x16x32_bf16(A.v, b2.v, a2, 0, 0, 0);
        a3 = __builtin_amdgcn_mfma_f32_16x16x32_bf16(A.v, b3.v, a3, 0, 0, 0);
        mn0 = fminf(fminf(mn0, fminf(a0[0], a1[0])), fminf(a2[0], a3[0]));
        mn1 = fminf(fminf(mn1, fminf(a0[1], a1[1])), fminf(a2[1], a3[1]));
        mn2 = fminf(fminf(mn2, fminf(a0[2], a1[2])), fminf(a2[2], a3[2]));
        mn3 = fminf(fminf(mn3, fminf(a0[3], a1[3])), fminf(a2[3], a3[3]));
    }
    mnsh[wv][qq * 4 + 0][col] = mn0;
    mnsh[wv][qq * 4 + 1][col] = mn1;
    mnsh[wv][qq * 4 + 2][col] = mn2;
    mnsh[wv][qq * 4 + 3][col] = mn3;
    if (tid < 16) cnt[tid] = 0;
    __syncthreads();

    {
        float tq[2];
#pragma unroll
        for (int q = 0; q < 2; ++q) {
            const int p = wv * 2 + q;
            float v = fminf(mnsh[lane >> 4][p][lane & 15],
                            mnsh[(lane >> 4) + 4][p][lane & 15]);
            tq[q] = rank16_of_64(v, lane) + KM_MFMA;
        }
        if (lane == 0) { taus[wv * 2] = tq[0]; taus[wv * 2 + 1] = tq[1]; }
    }
    __syncthreads();

    float mytau[4];
#pragma unroll
    for (int r = 0; r < 4; ++r) mytau[r] = taus[qq * 4 + r];   // D row = qq*4+r

    for (int t = 0; t < 64; t += 4) {
        U b0, b1, b2, b3;
        b0.u = bp[(size_t)t * 32];
        b1.u = bp[(size_t)(t + 1) * 32];
        b2.u = bp[(size_t)(t + 2) * 32];
        b3.u = bp[(size_t)(t + 3) * 32];
        f32x4 a0 = (f32x4){0.f, 0.f, 0.f, 0.f};
        f32x4 a1 = (f32x4){0.f, 0.f, 0.f, 0.f};
        f32x4 a2 = (f32x4){0.f, 0.f, 0.f, 0.f};
        f32x4 a3 = (f32x4){0.f, 0.f, 0.f, 0.f};
        a0 = __builtin_amdgcn_mfma_f32_16x16x32_bf16(A.v, b0.v, a0, 0, 0, 0);
        a1 = __builtin_amdgcn_mfma_f32_16x16x32_bf16(A.v, b1.v, a1, 0, 0, 0);
        a2 = __builtin_amdgcn_mfma_f32_16x16x32_bf16(A.v, b2.v, a2, 0, 0, 0);
        a3 = __builtin_amdgcn_mfma_f32_16x16x32_bf16(A.v, b3.v, a3, 0, 0, 0);
        const int c0 = cb + t * 16 + col;
        const int c1 = c0 + 16, c2 = c0 + 32, c3 = c0 + 48;
        bool any0 = (a0[0] <= mytau[0]) | (a0[1] <= mytau[1]) |
                    (a0[2] <= mytau[2]) | (a0[3] <= mytau[3]);
        bool any1 = (a1[0] <= mytau[0]) | (a1[1] <= mytau[1]) |
                    (a1[2] <= mytau[2]) | (a1[3] <= mytau[3]);
        bool any2 = (a2[0] <= mytau[0]) | (a2[1] <= mytau[1]) |
                    (a2[2] <= mytau[2]) | (a2[3] <= mytau[3]);
        bool any3 = (a3[0] <= mytau[0]) | (a3[1] <= mytau[1]) |
                    (a3[2] <= mytau[2]) | (a3[3] <= mytau[3]);
        if (any0 | any1) {
#pragma unroll
            for (int r = 0; r < 4; ++r) {
                if (a0[r] <= mytau[r]) {
                    int p = qq * 4 + r;
                    int pos = atomicAdd(&cnt[p], 1);
                    if (pos < CAP) sJ[p][pos] = c0;
                }
                if (a1[r] <= mytau[r]) {
                    int p = qq * 4 + r;
                    int pos = atomicAdd(&cnt[p], 1);
                    if (pos < CAP) sJ[p][pos] = c1;
                }
            }
        }
        if (any2 | any3) {
#pragma unroll
            for (int r = 0; r < 4; ++r) {
                if (a2[r] <= mytau[r]) {
                    int p = qq * 4 + r;
                    int pos = atomicAdd(&cnt[p], 1);
                    if (pos < CAP) sJ[p][pos] = c2;
                }
                if (a3[r] <= mytau[r]) {
                    int p = qq * 4 + r;
                    int pos = atomicAdd(&cnt[p], 1);
                    if (pos < CAP) sJ[p][pos] = c3;
                }
            }
        }
    }
    __syncthreads();

#pragma unroll
    for (int q = 0; q < 2; ++q) {
        const int p = wv * 2 + q;
        int ns = cnt[p]; ns = (ns > CAP) ? CAP : ns;   // >= 16 guaranteed
        const float4 sp = P[i0 + p];
        float dl[2]; int jl[2];
#pragma unroll
        for (int slot = 0; slot < 2; ++slot) {
            int sidx = slot * 64 + lane;
            bool act = sidx < ns;
            int js = act ? sJ[p][sidx] : 0;
            float4 cc = P[js];
            float dot = __fmul_rn(sp.x, cc.x);
            dot = __fmaf_rn(sp.y, cc.y, dot);
            dot = __fmaf_rn(sp.z, cc.z, dot);
            float d = __fsub_rn(__fadd_rn(sp.w, cc.w), __fmul_rn(2.0f, dot));
            if (act) bufD[p][sidx] = d;
            dl[slot] = d; jl[slot] = js;
        }
        int r0 = 0, r1 = 0;
        for (int mm = 0; mm < ns; ++mm) {
            float dm = bufD[p][mm]; int jm = sJ[p][mm];
            r0 += (dm < dl[0]) || (dm == dl[0] && jm < jl[0]);
            r1 += (dm < dl[1]) || (dm == dl[1] && jm < jl[1]);
        }
        if (lane < ns && r0 < KNN)
            nbr_out_rows[(size_t)(ptb + p) * 64 + r0] = jl[0];
        if (64 + lane < ns && r1 < KNN)
            nbr_out_rows[(size_t)(ptb + p) * 64 + r1] = jl[1];
    }
}

// ============== KNN v9 (green 77us): mid fallback if ws < 768KB ==============
__global__ __launch_bounds__(256, 8) void knn9_kernel(const float4* __restrict__ pv,
                                                      int* __restrict__ nbr_out_rows) {
    __shared__ float  bufD[4][2][CAP];
    __shared__ int    bufJ[4][2][CAP];

    const int tid = threadIdx.x, lane = tid & 63, wv = tid >> 6;
    const int pt0 = (blockIdx.x * 4 + wv) * 2;
    const int b = pt0 >> 13, i0 = pt0 & (NPTS - 1);
    const float4* P = pv + (size_t)b * NPTS;

    float4 sp[2];
    float ax[2], ay[2], az[2];
#pragma unroll
    for (int p = 0; p < 2; ++p) {
        sp[p] = P[i0 + p];
        ax[p] = -2.0f * sp[p].x; ay[p] = -2.0f * sp[p].y; az[p] = -2.0f * sp[p].z;
    }

    float mn[2] = {INFINITY, INFINITY};
    for (int t = 0; t < 16; ++t) {
        float4 c0 = P[t * 256 + lane];
        float4 c1 = P[t * 256 + 64 + lane];
        float4 c2 = P[t * 256 + 128 + lane];
        float4 c3 = P[t * 256 + 192 + lane];
#pragma unroll
        for (int p = 0; p < 2; ++p) {
            float f0 = __fmaf_rn(ax[p], c0.x, __fmaf_rn(ay[p], c0.y, __fmaf_rn(az[p], c0.z, c0.w)));
            float f1 = __fmaf_rn(ax[p], c1.x, __fmaf_rn(ay[p], c1.y, __fmaf_rn(az[p], c1.z, c1.w)));
            float f2 = __fmaf_rn(ax[p], c2.x, __fmaf_rn(ay[p], c2.y, __fmaf_rn(az[p], c2.z, c2.w)));
            float f3 = __fmaf_rn(ax[p], c3.x, __fmaf_rn(ay[p], c3.y, __fmaf_rn(az[p], c3.z, c3.w)));
            mn[p] = fminf(fminf(fminf(mn[p], f0), fminf(f1, f2)), f3);
        }
    }

    float tau[2];
#pragma unroll
    for (int p = 0; p < 2; ++p)
        tau[p] = rank16_of_64(mn[p], lane) + KMARGIN;

    int base[2] = {0, 0};
    for (int t = 0; t < 32; ++t) {
        float4 c[4];
#pragma unroll
        for (int k = 0; k < 4; ++k) c[k] = P[t * 256 + k * 64 + lane];
        bool pr[4][2];
        bool anyl = false;
#pragma unroll
        for (int k = 0; k < 4; ++k)
#pragma unroll
            for (int p = 0; p < 2; ++p) {
                float f = __fmaf_rn(ax[p], c[k].x,
                          __fmaf_rn(ay[p], c[k].y,
                          __fmaf_rn(az[p], c[k].z, c[k].w)));
                pr[k][p] = (f <= tau[p]);
                anyl |= pr[k][p];
            }
        if (__ballot(anyl) == 0ull) continue;
#pragma unroll
        for (int k = 0; k < 4; ++k) {
            u64 anyk = __ballot(pr[k][0] | pr[k][1]);
            if (anyk == 0ull) continue;
            int j = t * 256 + k * 64 + lane;
#pragma unroll
            for (int p = 0; p < 2; ++p) {
                u64 mk = __ballot(pr[k][p]);
                if (mk != 0ull) {
                    if (pr[k][p]) {
                        int pos = base[p] + (int)__popcll(mk & ((1ull << lane) - 1ull));
                        if (pos < CAP) bufJ[wv][p][pos] = j;
                    }
                    base[p] += (int)__popcll(mk);
                }
            }
        }
    }

#pragma unroll
    for (int p = 0; p < 2; ++p) {
        int ns = base[p]; ns = (ns > CAP) ? CAP : ns;
        float dloc[2]; int jloc[2];
#pragma unroll
        for (int slot = 0; slot < 2; ++slot) {
            int sidx = slot * 64 + lane;
            bool act = sidx < ns;
            int js = act ? bufJ[wv][p][sidx] : 0;
            float4 cc = P[js];
            float dot = __fmul_rn(sp[p].x, cc.x);
            dot = __fmaf_rn(sp[p].y, cc.y, dot);
            dot = __fmaf_rn(sp[p].z, cc.z, dot);
            float d = __fsub_rn(__fadd_rn(sp[p].w, cc.w), __fmul_rn(2.0f, dot));
            if (act) bufD[wv][p][sidx] = d;
            dloc[slot] = d; jloc[slot] = js;
        }
        int r0 = 0, r1 = 0;
        for (int mm = 0; mm < ns; ++mm) {
            float dm = bufD[wv][p][mm]; int jm = bufJ[wv][p][mm];
            r0 += (dm < dloc[0]) || (dm == dloc[0] && jm < jloc[0]);
            r1 += (dm < dloc[1]) || (dm == dloc[1] && jm < jloc[1]);
        }
        if (lane < ns && r0 < KNN)
            nbr_out_rows[(size_t)(pt0 + p) * 64 + r0] = jloc[0];
        if (64 + lane < ns && r1 < KNN)
            nbr_out_rows[(size_t)(pt0 + p) * 64 + r1] = jloc[1];
    }
}

// ============== KNN fallback (used only if ws too small) ==============
__global__ __launch_bounds__(256) void knn_kernel(const float* __restrict__ verts,
                                                  int* nbr_out_rows) {
    __shared__ float4 tilebuf[TILE];
    __shared__ float  bufD[4][CAP];
    __shared__ int    bufJ[4][CAP];

    const int tid = threadIdx.x, lane = tid & 63, wv = tid >> 6;
    const int pt = blockIdx.x * 4 + wv;
    const int b = pt >> 13, i = pt & (NPTS - 1);
    const float* vb = verts + (size_t)b * NPTS * 3;

    const float xi = vb[3 * i], yi = vb[3 * i + 1], zi = vb[3 * i + 2];
    const float sqi = __fadd_rn(__fadd_rn(__fmul_rn(xi, xi), __fmul_rn(yi, yi)),
                                __fmul_rn(zi, zi));

    float m_d = INFINITY;
    for (int t = 0; t < NPTS / TILE; ++t) {
        __syncthreads();
        for (int s = 0; s < TILE / 256; ++s) {
            int p = t * TILE + s * 256 + tid;
            float px = vb[3 * p], py = vb[3 * p + 1], pz = vb[3 * p + 2];
            float sq = __fadd_rn(__fadd_rn(__fmul_rn(px, px), __fmul_rn(py, py)),
                                 __fmul_rn(pz, pz));
            tilebuf[s * 256 + tid] = make_float4(px, py, pz, sq);
        }
        __syncthreads();
        for (int it = 0; it < TILE / 64; ++it) {
            float4 c = tilebuf[it * 64 + lane];
            float dot = __fmul_rn(xi, c.x);
            dot = __fmaf_rn(yi, c.y, dot);
            dot = __fmaf_rn(zi, c.z, dot);
            float d = __fsub_rn(__fadd_rn(sqi, c.w), __fmul_rn(2.0f, dot));
            m_d = fminf(m_d, d);
        }
    }
    __shared__ float minv[4][64];
    minv[wv][lane] = m_d;
    __syncthreads();
    int rnk = 0;
    for (int mm = 0; mm < 64; ++mm) {
        float vm = minv[wv][mm];
        rnk += (vm < m_d) || (vm == m_d && mm < lane);
    }
    u64 bal = __ballot(rnk == 15);
    float tau = __shfl(m_d, __ffsll(bal) - 1, 64);

    int base = 0;
    for (int t = 0; t < NPTS / TILE; ++t) {
        __syncthreads();
        for (int s = 0; s < TILE / 256; ++s) {
            int p = t * TILE + s * 256 + tid;
            float px = vb[3 * p], py = vb[3 * p + 1], pz = vb[3 * p + 2];
            float sq = __fadd_rn(__fadd_rn(__fmul_rn(px, px), __fmul_rn(py, py)),
                                 __fmul_rn(pz, pz));
            tilebuf[s * 256 + tid] = make_float4(px, py, pz, sq);
        }
        __syncthreads();
        for (int it = 0; it < TILE / 64; ++it) {
            int jl = it * 64 + lane;
            float4 c = tilebuf[jl];
            float dot = __fmul_rn(xi, c.x);
            dot = __fmaf_rn(yi, c.y, dot);
            dot = __fmaf_rn(zi, c.z, dot);
            float d = __fsub_rn(__fadd_rn(sqi, c.w), __fmul_rn(2.0f, dot));
            bool pred = (d <= tau);
            u64 mask = __ballot(pred);
            if (pred) {
                int pos = base + (int)__popcll(mask & ((1ull << lane) - 1ull));
                if (pos < CAP) { bufD[wv][pos] = d; bufJ[wv][pos] = t * TILE + jl; }
            }
            base += (int)__popcll(mask);
        }
    }
    int ns = (base > CAP) ? CAP : base;
    __syncthreads();
#pragma unroll
    for (int slot = 0; slot < 2; ++slot) {
        int sidx = slot * 64 + lane;
        if (sidx < ns) {
            float ds = bufD[wv][sidx];
            int   js = bufJ[wv][sidx];
            int rank = 0;
            for (int mm = 0; mm < ns; ++mm) {
                float dm = bufD[wv][mm];
                int   jm = bufJ[wv][mm];
                rank += (dm < ds) || (dm == ds && jm < js);
            }
            if (rank < KNN) nbr_out_rows[(size_t)pt * 64 + rank] = js;
        }
    }
}

// ============ edge8 v3 (green, r10/r12): W2F in LDS + gather prefetch ========
__global__ __launch_bounds__(512, 2) void edge8_kernel(
    const float* __restrict__ verts, const float* __restrict__ feats,
    const float* __restrict__ W1, const float* __restrict__ b1,
    const float* __restrict__ g1, const float* __restrict__ be1,
    const float* __restrict__ W2, const float* __restrict__ b2,
    const float* __restrict__ Wo1, const float* __restrict__ bo1,
    const float* __restrict__ go_, const float* __restrict__ beo,
    const float* __restrict__ Wo2, const float* __restrict__ bo2,
    float* out)   // rows hold knn idx on entry; final output on exit
{
    __shared__ u16 EPw[8][4][64][8];    // 32 KB: per-wave E/P A-frag region
    __shared__ u16 W1F[3][8][64][8];    // 24 KB (phase2: Wo1 frags in kt 0..1)
    __shared__ u16 W2F[4][4][64][8];    // 8 KB W2 B-frags (phase2: Wo2)
    __shared__ float b1s[HID], g1s[HID], be1s[HID];
    __shared__ float b2s[COUT];
    __shared__ float meansh[32][68];    // 8.5 KB; phase2: staging for out rows

    const int tid  = threadIdx.x;
    const int lane = tid & 63, wv = tid >> 6;    // wv 0..7
    const int quad = lane >> 4, n16 = lane & 15;

    // ---- stage W1 as B-fragments ----
    for (int s = tid; s < 3 * 8 * 64; s += 512) {
        int kt = s >> 9, nt = (s >> 6) & 7, ln = s & 63;
        int q = ln >> 4, nn = ln & 15;
        int col = nt * 16 + nn;
        union { bf16x8 v; unsigned u[4]; } pk;
#pragma unroll
        for (int jj = 0; jj < 4; ++jj) {
            int k0 = kt * 32 + q * 8 + jj * 2;
            float a  = (k0     < EIN) ? W1[(size_t)k0 * HID + col]       : 0.0f;
            float bq = (k0 + 1 < EIN) ? W1[(size_t)(k0 + 1) * HID + col] : 0.0f;
            pk.u[jj] = pk2(a, bq);
        }
        *(bf16x8*)&W1F[kt][nt][ln][0] = pk.v;
    }
    // ---- stage W2 as B-fragments (cooperative; shared across waves) ----
    for (int s = tid; s < 4 * 4 * 64; s += 512) {
        int kt2 = s >> 8, nt2 = (s >> 6) & 3, ln = s & 63;
        int q = ln >> 4, nn = ln & 15;
        int o = nt2 * 16 + nn;
        union { bf16x8 v; unsigned u[4]; } pk;
#pragma unroll
        for (int jj = 0; jj < 4; ++jj) {
            int k0 = kt2 * 32 + q * 8 + jj * 2;
            pk.u[jj] = pk2(W2[(size_t)k0 * COUT + o],
                           W2[(size_t)(k0 + 1) * COUT + o]);
        }
        *(bf16x8*)&W2F[kt2][nt2][ln][0] = pk.v;
    }
    if (tid < HID) { b1s[tid] = b1[tid]; g1s[tid] = g1[tid]; be1s[tid] = be1[tid]; }
    if (tid >= HID && tid < HID + COUT) b2s[tid - HID] = b2[tid - HID];
    __syncthreads();   // W1F + W2F + biases visible to all waves

    const int ptb = blockIdx.x * 32;
    const int bb  = ptb >> 13;
    const float* fb  = feats + (size_t)bb * NPTS * CIN;
    const float* vbk = verts + (size_t)bb * NPTS * 3;
    const int ptw = ptb + wv * 4;              // this wave's 4 points
    const int ipw = ptw & (NPTS - 1);

    // hoisted LN operands (point-independent)
    float b1v[8], g1v[8], bev[8];
#pragma unroll
    for (int nt = 0; nt < 8; ++nt) {
        b1v[nt] = b1s[nt * 16 + n16];
        g1v[nt] = g1s[nt * 16 + n16];
        bev[nt] = be1s[nt * 16 + n16];
    }

    const int k16 = lane & 15;
    const int qq  = lane >> 4;

    int jnv[4];
#pragma unroll
    for (int pp = 0; pp < 4; ++pp)
        jnv[pp] = ((const int*)out)[(size_t)(ptw + pp) * 64 + k16];

    // ---- preload pp=0 gathers ----
    float4 nA, nB, sA, sB;
    float rx = 0.f, ry = 0.f, rz = 0.f;
    {
        const int jn = jnv[0], ipn = ipw;
        const float* nsrc = fb + (size_t)jn * CIN + qq * 8;
        nA = *(const float4*)nsrc; nB = *(const float4*)(nsrc + 4);
        const float* ssrc = fb + (size_t)ipn * CIN + qq * 8;
        sA = *(const float4*)ssrc; sB = *(const float4*)(ssrc + 4);
        if (qq == 0) {
            rx = vbk[3 * jn]     - vbk[3 * ipn];
            ry = vbk[3 * jn + 1] - vbk[3 * ipn + 1];
            rz = vbk[3 * jn + 2] - vbk[3 * ipn + 2];
        }
    }

#pragma unroll
    for (int pp = 0; pp < 4; ++pp) {
        // ---- pack + store E from prefetched regs (3 b128 per lane) ----
        {
            union { bf16x8 v; unsigned u[4]; } e0, e1, e2;
            e0.u[0] = pk2(nA.x, nA.y); e0.u[1] = pk2(nA.z, nA.w);
            e0.u[2] = pk2(nB.x, nB.y); e0.u[3] = pk2(nB.z, nB.w);
            e1.u[0] = pk2(sA.x, sA.y); e1.u[1] = pk2(sA.z, sA.w);
            e1.u[2] = pk2(sB.x, sB.y); e1.u[3] = pk2(sB.z, sB.w);
            e2.u[0] = e2.u[1] = e2.u[2] = e2.u[3] = 0u;
            if (qq == 0) { e2.u[0] = pk2(rx, ry); e2.u[1] = pk2(rz, 0.0f); }
            *(bf16x8*)&EPw[wv][0][lane][0] = e0.v;
            *(bf16x8*)&EPw[wv][1][lane][0] = e1.v;
            *(bf16x8*)&EPw[wv][2][lane][0] = e2.v;
        }

        // ---- issue NEXT point's gathers; latency hides under compute below ----
        if (pp < 3) {
            const int jn = jnv[pp + 1], ipn = ipw + pp + 1;
            const float* nsrc = fb + (size_t)jn * CIN + qq * 8;
            nA = *(const float4*)nsrc; nB = *(const float4*)(nsrc + 4);
            const float* ssrc = fb + (size_t)ipn * CIN + qq * 8;
            sA = *(const float4*)ssrc; sB = *(const float4*)(ssrc + 4);
            if (qq == 0) {
                rx = vbk[3 * jn]     - vbk[3 * ipn];
                ry = vbk[3 * jn + 1] - vbk[3 * ipn + 1];
                rz = vbk[3 * jn + 2] - vbk[3 * ipn + 2];
            }
        }

        // ---- GEMM1: D1[16 edges][128 hid] ----
        f32x4 acc[8];
#pragma unroll
        for (int nt = 0; nt < 8; ++nt) acc[nt] = (f32x4){0.f, 0.f, 0.f, 0.f};
#pragma unroll
        for (int kt = 0; kt < 3; ++kt) {
            bf16x8 a = *(bf16x8*)&EPw[wv][kt][lane][0];
#pragma unroll
            for (int nt = 0; nt < 8; ++nt) {
                bf16x8 bfr = *(bf16x8*)&W1F[kt][nt][lane][0];
                acc[nt] = __builtin_amdgcn_mfma_f32_16x16x32_bf16(a, bfr, acc[nt], 0, 0, 0);
            }
        }

        // ---- bias + LN (16-lane groups) ----
        float s1[4] = {0,0,0,0}, s2[4] = {0,0,0,0};
#pragma unroll
        for (int nt = 0; nt < 8; ++nt)
#pragma unroll
            for (int r = 0; r < 4; ++r) {
                float x = acc[nt][r] + b1v[nt];
                s1[r] += x; s2[r] += x * x;
            }
#pragma unroll
        for (int r = 0; r < 4; ++r) {
#pragma unroll
            for (int off = 1; off < 16; off <<= 1) {
                s1[r] += __shfl_xor(s1[r], off, 64);
                s2[r] += __shfl_xor(s2[r], off, 64);
            }
        }
        float mu[4], rs[4];
#pragma unroll
        for (int r = 0; r < 4; ++r) {
            mu[r] = s1[r] * (1.0f / HID);
            float var = s2[r] * (1.0f / HID) - mu[r] * mu[r];
            rs[r] = rsqrtf(var + 1e-5f);
        }

        // ---- GELU + pack into A-frag layout (P over EPw[wv]) ----
#pragma unroll
        for (int nt = 0; nt < 8; ++nt) {
            int kt2 = nt >> 1;
            int q2  = (nt * 2 + (n16 >> 3)) & 3;
            int jj  = n16 & 7;
#pragma unroll
            for (int r = 0; r < 4; ++r) {
                float x  = acc[nt][r] + b1v[nt];
                float xn = (x - mu[r]) * rs[r] * g1v[nt] + bev[nt];
                EPw[wv][kt2][quad * 4 + r + 16 * q2][jj] = (u16)f2b(gelu_t(xn));
            }
        }

        // ---- GEMM2: D2[16 edges][64 out] ----
        f32x4 acc2[4];
#pragma unroll
        for (int nt2 = 0; nt2 < 4; ++nt2) acc2[nt2] = (f32x4){0.f, 0.f, 0.f, 0.f};
#pragma unroll
        for (int kt2 = 0; kt2 < 4; ++kt2) {
            bf16x8 a2 = *(bf16x8*)&EPw[wv][kt2][lane][0];
#pragma unroll
            for (int nt2 = 0; nt2 < 4; ++nt2) {
                bf16x8 bfr2 = *(bf16x8*)&W2F[kt2][nt2][lane][0];
                acc2[nt2] = __builtin_amdgcn_mfma_f32_16x16x32_bf16(a2, bfr2, acc2[nt2], 0, 0, 0);
            }
        }

        // ---- mean over 16 edges (+b2) -> meansh ----
#pragma unroll
        for (int nt2 = 0; nt2 < 4; ++nt2) {
            float cs = acc2[nt2][0] + acc2[nt2][1] + acc2[nt2][2] + acc2[nt2][3];
            cs += __shfl_xor(cs, 16, 64);
            cs += __shfl_xor(cs, 32, 64);
            if (quad == 0) {
                int o = nt2 * 16 + n16;
                meansh[wv * 4 + pp][o] = cs * (1.0f / KNN) + b2s[o];
            }
        }
    }

    // ======== phase 2: point MLP (MFMA) for the block's 32 points ========
    __syncthreads();   // all means written; safe to overlay W1F/W2F/biases

    for (int s = tid; s < 2 * 8 * 64; s += 512) {   // Wo1 B-frags (K=64)
        int kt = s >> 9, nt = (s >> 6) & 7, ln = s & 63;
        int q = ln >> 4, nn = ln & 15;
        int col = nt * 16 + nn;
        union { bf16x8 v; unsigned u[4]; } pk;
#pragma unroll
        for (int jj = 0; jj < 4; ++jj) {
            int k0 = kt * 32 + q * 8 + jj * 2;
            pk.u[jj] = pk2(Wo1[(size_t)k0 * HID + col],
                           Wo1[(size_t)(k0 + 1) * HID + col]);
        }
        *(bf16x8*)&W1F[kt][nt][ln][0] = pk.v;
    }
    for (int s = tid; s < 4 * 4 * 64; s += 512) {   // Wo2 B-frags
        int kt2 = s >> 8, nt2 = (s >> 6) & 3, ln = s & 63;
        int q = ln >> 4, nn = ln & 15;
        int o = nt2 * 16 + nn;
        union { bf16x8 v; unsigned u[4]; } pk;
#pragma unroll
        for (int jj = 0; jj < 4; ++jj) {
            int k0 = kt2 * 32 + q * 8 + jj * 2;
            pk.u[jj] = pk2(Wo2[(size_t)k0 * COUT + o],
                           Wo2[(size_t)(k0 + 1) * COUT + o]);
        }
        *(bf16x8*)&W2F[kt2][nt2][ln][0] = pk.v;
    }
    if (tid < HID) { b1s[tid] = bo1[tid]; g1s[tid] = go_[tid]; be1s[tid] = beo[tid]; }
    if (tid >= HID && tid < HID + COUT) b2s[tid - HID] = bo2[tid - HID];
    __syncthreads();

    if (wv < 2) {   // wave 0: points 0-15; wave 1: points 16-31
        const int pr0 = wv * 16;
        bf16x8 af[2];
#pragma unroll
        for (int kt = 0; kt < 2; ++kt) {
            const float* mrow = &meansh[pr0 + n16][kt * 32 + quad * 8];
            float4 A = *(const float4*)mrow, B4 = *(const float4*)(mrow + 4);
            union { bf16x8 v; unsigned u[4]; } pk;
            pk.u[0] = pk2(A.x, A.y); pk.u[1] = pk2(A.z, A.w);
            pk.u[2] = pk2(B4.x, B4.y); pk.u[3] = pk2(B4.z, B4.w);
            af[kt] = pk.v;
        }

        f32x4 acc[8];
#pragma unroll
        for (int nt = 0; nt < 8; ++nt) acc[nt] = (f32x4){0.f, 0.f, 0.f, 0.f};
#pragma unroll
        for (int kt = 0; kt < 2; ++kt)
#pragma unroll
            for (int nt = 0; nt < 8; ++nt) {
                bf16x8 bfr = *(bf16x8*)&W1F[kt][nt][lane][0];
                acc[nt] = __builtin_amdgcn_mfma_f32_16x16x32_bf16(af[kt], bfr, acc[nt], 0, 0, 0);
            }

        float pb1[8], pg1[8], pbe[8];
#pragma unroll
        for (int nt = 0; nt < 8; ++nt) {
            pb1[nt] = b1s[nt * 16 + n16];
            pg1[nt] = g1s[nt * 16 + n16];
            pbe[nt] = be1s[nt * 16 + n16];
        }
        float s1[4] = {0,0,0,0}, s2[4] = {0,0,0,0};
#pragma unroll
        for (int nt = 0; nt < 8; ++nt)
#pragma unroll
            for (int r = 0; r < 4; ++r) {
                float x = acc[nt][r] + pb1[nt];
                s1[r] += x; s2[r] += x * x;
            }
#pragma unroll
        for (int r = 0; r < 4; ++r) {
#pragma unroll
            for (int off = 1; off < 16; off <<= 1) {
                s1[r] += __shfl_xor(s1[r], off, 64);
                s2[r] += __shfl_xor(s2[r], off, 64);
            }
        }
#pragma unroll
        for (int nt = 0; nt < 8; ++nt) {
            int kt2 = nt >> 1;
            int q2  = (nt * 2 + (n16 >> 3)) & 3;
            int jj  = n16 & 7;
#pragma unroll
            for (int r = 0; r < 4; ++r) {
                float mu = s1[r] * (1.0f / HID);
                float var = s2[r] * (1.0f / HID) - mu * mu;
                float rs = rsqrtf(var + 1e-5f);
                float x  = acc[nt][r] + pb1[nt];
                float xn = (x - mu) * rs * pg1[nt] + pbe[nt];
                EPw[wv][kt2][quad * 4 + r + 16 * q2][jj] = (u16)f2b(gelu_t(xn));
            }
        }

        f32x4 acc2[4];
#pragma unroll
        for (int nt2 = 0; nt2 < 4; ++nt2) acc2[nt2] = (f32x4){0.f, 0.f, 0.f, 0.f};
#pragma unroll
        for (int kt2 = 0; kt2 < 4; ++kt2) {
            bf16x8 a2 = *(bf16x8*)&EPw[wv][kt2][lane][0];
#pragma unroll
            for (int nt2 = 0; nt2 < 4; ++nt2) {
                bf16x8 bfr2 = *(bf16x8*)&W2F[kt2][nt2][lane][0];
                acc2[nt2] = __builtin_amdgcn_mfma_f32_16x16x32_bf16(a2, bfr2, acc2[nt2], 0, 0, 0);
            }
        }

        // stage final rows into meansh (means fully consumed by af above;
        // cross-wave rows are disjoint: wave w writes rows [16w,16w+16))
#pragma unroll
        for (int nt2 = 0; nt2 < 4; ++nt2) {
            int o = nt2 * 16 + n16;
#pragma unroll
            for (int r = 0; r < 4; ++r)
                meansh[pr0 + quad * 4 + r][o] = acc2[nt2][r] + b2s[o];
        }
    }
    __syncthreads();

    // coalesced float4 store: thread -> (point = tid>>4, 4 channels)
    {
        int p = tid >> 4, c = (tid & 15) * 4;
        float4 v = *(const float4*)&meansh[p][c];
        *(float4*)&out[(size_t)(ptb + p) * 64 + c] = v;
    }
}

extern "C" void kernel_launch(void* const* d_in, const int* in_sizes, int n_in,
                              void* d_out, int out_size, void* d_ws, size_t ws_size,
                              hipStream_t stream) {
    const float* verts = (const float*)d_in[0];
    const float* feats = (const float*)d_in[1];
    const float* W1  = (const float*)d_in[2];
    const float* b1  = (const float*)d_in[3];
    const float* g1  = (const float*)d_in[4];
    const float* be1 = (const float*)d_in[5];
    const float* W2  = (const float*)d_in[6];
    const float* b2  = (const float*)d_in[7];
    const float* Wo1 = (const float*)d_in[8];
    const float* bo1 = (const float*)d_in[9];
    const float* go_ = (const float*)d_in[10];
    const float* beo = (const float*)d_in[11];
    const float* Wo2 = (const float*)d_in[12];
    const float* bo2 = (const float*)d_in[13];
    float* out = (float*)d_out;

    (void)in_sizes; (void)n_in; (void)out_size;

    const size_t pv_bytes = (size_t)BATCH * NPTS * sizeof(float4);  // 256 KB
    const size_t bf_bytes = (size_t)BATCH * NPTS * 32;              // 512 KB
    if (ws_size >= pv_bytes + bf_bytes) {
        float4* pv = (float4*)d_ws;
        uint4*  bf = (uint4*)((char*)d_ws + pv_bytes);
        prep2_kernel<<<(BATCH * NPTS + 255) / 256, 256, 0, stream>>>(verts, pv, bf);
        knn12_kernel<<<(BATCH * NPTS) / 16, 512, 0, stream>>>(pv, bf, (int*)out);
    } else if (ws_size >= pv_bytes) {
        float4* pv = (float4*)d_ws;
        prep_kernel<<<(BATCH * NPTS + 255) / 256, 256, 0, stream>>>(verts, pv);
        knn9_kernel<<<(BATCH * NPTS) / 8, 256, 0, stream>>>(pv, (int*)out);
    } else {
        knn_kernel<<<(BATCH * NPTS) / 4, 256, 0, stream>>>(verts, (int*)out);
    }
    edge8_kernel<<<(BATCH * NPTS) / 32, 512, 0, stream>>>(
        verts, feats, W1, b1, g1, be1, W2, b2,
        Wo1, bo1, go_, beo, Wo2, bo2, out);
}